// Round 9
// baseline (552.877 us; speedup 1.0000x reference)
//
#include <hip/hip_runtime.h>

typedef __attribute__((ext_vector_type(8))) short short8v;
typedef __attribute__((ext_vector_type(4))) float f32x4;

typedef const __attribute__((address_space(1))) void gvoid_t;
typedef __attribute__((address_space(3))) void svoid_t;

__device__ __forceinline__ unsigned short f2b(float f) {
    unsigned u = __float_as_uint(f);
    unsigned r = (u + 0x7fffu + ((u >> 16) & 1u)) >> 16;
    return (unsigned short)r;
}
__device__ __forceinline__ float b2f(unsigned short h) {
    return __uint_as_float((unsigned)h << 16);
}

// ---------------- elementwise / setup kernels ----------------

__global__ void k_build_A(const float* __restrict__ adj,
                          const float* __restrict__ alpha,
                          float* __restrict__ Xs, unsigned short* __restrict__ Xb,
                          int n, float scale)
{
    int j = blockIdx.x * 256 + threadIdx.x;
    int i = blockIdx.y;
    if (j >= n) return;
    size_t idx = (size_t)i * n + j;
    float s = 1.f / (1.f + expf(-alpha[i]));
    float v = scale * s * (adj[idx] - (i == j ? 1.f : 0.f));
    Xs[idx] = v;
    Xb[idx] = f2b(v);
}

__global__ void k_build_EW(const float* __restrict__ w,
                           const float* __restrict__ d,
                           unsigned short* __restrict__ Eb,
                           unsigned short* __restrict__ Edb,
                           float* __restrict__ Edf, int h)
{
    int j = blockIdx.x * 256 + threadIdx.x;
    int i = blockIdx.y;
    if (j >= h) return;
    size_t idx = (size_t)i * h + j;
    float e = w[idx] - (i == j ? 1.f : 0.f);
    float dc = fminf(fmaxf(d[j], 0.f), 1.f);
    Eb[idx] = f2b(e);
    float ed = e * dc;
    Edb[idx] = f2b(ed);
    Edf[idx] = ed;
}

__global__ void k_build_R(const float* __restrict__ Ed,
                          const float* __restrict__ d,
                          float* __restrict__ R, int h, float dt)
{
    __shared__ float tile[32][33];
    int bx = blockIdx.x * 32, by = blockIdx.y * 32;
    int tx = threadIdx.x, ty = threadIdx.y;
    #pragma unroll
    for (int r = 0; r < 32; r += 8)
        tile[ty + r][tx] = Ed[(size_t)(bx + ty + r) * h + by + tx];
    __syncthreads();
    #pragma unroll
    for (int r = 0; r < 32; r += 8) {
        int i = by + ty + r, j = bx + tx;
        float v = Ed[(size_t)i * h + j] + tile[tx][ty + r];
        if (i == j) v += fminf(fmaxf(d[i], 0.f), 1.f) - 1.f;
        R[(size_t)i * h + j] = dt * v;
    }
}

__global__ void k_tsplit(const float* __restrict__ in,
                         unsigned short* __restrict__ outT, int R, int C)
{
    __shared__ float tile[32][33];
    int bx = blockIdx.x * 32, by = blockIdx.y * 32;
    int tx = threadIdx.x, ty = threadIdx.y;
    #pragma unroll
    for (int r = 0; r < 32; r += 8)
        tile[ty + r][tx] = in[(size_t)(by + ty + r) * C + bx + tx];
    __syncthreads();
    #pragma unroll
    for (int r = 0; r < 32; r += 8)
        outT[(size_t)(bx + ty + r) * R + by + tx] = f2b(tile[tx][ty + r]);
}

// ------- bf16 MFMA GEMM: BM=FM*32 x BN=FN*32 tile, BK=64, 2-buffer ----------
// counted-vmcnt pipeline (R8-proven). 256 threads = 4 waves (2x2), per-wave
// (FM*16)x(FN*16) fragment grid -> LDS-read ratio 8*2*FM*FN/(FM+FN) FLOP/B.
// acc = A @ B  (A: MxK bf16 row-major; BT: NxK bf16 row-major = B transposed)
// v  = alpha*acc + beta*D + g2*D2 + g3*b2f(Db) -> C (f32), Cb (bf16), CbT ([N][M] bf16)
// v2 = pa*acc + pb*D + pc*b2f(Db)              -> Cb2 (bf16)
// v3 = qa*acc + qb*D + qc*b2f(Db)              -> Cb3 (bf16)
// LDS: linear global_load_lds dest; XOR-swizzled source + swizzled ds_read
// (rule #21 both-sides) -> 0 bank conflicts (R5-R8 verified).
// XCD row-stripe swizzle: XCD q owns gridDim.y/8 row-blocks x all cols.

template<int FM, int FN, int MW>
__global__ __launch_bounds__(256, MW)
void gemm_bf16(const unsigned short* __restrict__ A,
               const unsigned short* __restrict__ BT,
               float* __restrict__ C,
               unsigned short* __restrict__ Cb,
               unsigned short* __restrict__ Cb2,
               unsigned short* __restrict__ Cb3,
               unsigned short* __restrict__ CbT,
               const float* __restrict__ D,
               const float* __restrict__ D2,
               const unsigned short* __restrict__ Db,
               int M, int N, int K,
               float alpha, float beta, float g2, float g3,
               float pa, float pb, float pc,
               float qa, float qb, float qc)
{
    constexpr int BM = FM * 32, BN = FN * 32, BK = 64;
    constexpr int AIT = BM * BK / (8 * 256);   // 16B chunks per thread (A)
    constexpr int BIT = BN * BK / (8 * 256);
    constexpr int LPT = AIT + BIT;
    __shared__ unsigned short As[2][BM * BK];
    __shared__ unsigned short Bs[2][BN * BK];

    // XCD row-stripe swizzle (requires gridDim.y % 8 == 0 or gridDim.y == 8)
    int bid = blockIdx.y * gridDim.x + blockIdx.x;
    int rpx = gridDim.y >> 3;
    int q = bid & 7, c = bid >> 3;
    int by = q * rpx + (c % rpx);
    int bx = c / rpx;

    const int tid  = threadIdx.x;
    const int lane = tid & 63;
    const int wave = tid >> 6;
    const int wr = wave >> 1, wc = wave & 1;   // 2 x 2 wave grid
    const int l16 = lane & 15, l4 = lane >> 4;
    const int brow = by * BM, bcol = bx * BN;

    f32x4 acc[FM][FN];
    #pragma unroll
    for (int m = 0; m < FM; ++m)
        #pragma unroll
        for (int j = 0; j < FN; ++j)
            acc[m][j] = (f32x4){0.f, 0.f, 0.f, 0.f};

    const unsigned short* Ab = A + (size_t)brow * K;
    const unsigned short* Bb = BT + (size_t)bcol * K;
    const int nt = K / BK;

    auto stage = [&](int b, int k0) {
        #pragma unroll
        for (int it = 0; it < AIT; ++it) {
            int cb = it * 256 + wave * 64;          // wave-uniform chunk base
            int ch = cb + lane;
            int r = ch >> 3, cc = ch & 7;
            int cs = cc ^ (r & 7);                  // inverse-swizzled source
            __builtin_amdgcn_global_load_lds(
                (gvoid_t*)(Ab + (size_t)r * K + k0 + cs * 8),
                (svoid_t*)(&As[b][cb * 8]), 16, 0, 0);
        }
        #pragma unroll
        for (int it = 0; it < BIT; ++it) {
            int cb = it * 256 + wave * 64;
            int ch = cb + lane;
            int r = ch >> 3, cc = ch & 7;
            int cs = cc ^ (r & 7);
            __builtin_amdgcn_global_load_lds(
                (gvoid_t*)(Bb + (size_t)r * K + k0 + cs * 8),
                (svoid_t*)(&Bs[b][cb * 8]), 16, 0, 0);
        }
    };

    stage(0, 0);
    stage(1, BK);

    for (int t = 0; t < nt; ++t) {
        const int cur = t & 1;
        if (t + 1 < nt) {
            asm volatile("s_waitcnt vmcnt(%0)" :: "i"(LPT) : "memory");
        } else {
            asm volatile("s_waitcnt vmcnt(0)" ::: "memory");
        }
        __builtin_amdgcn_s_barrier();
        asm volatile("" ::: "memory");
        __builtin_amdgcn_sched_barrier(0);

        short8v af[FM][2], bf[FN][2];
        #pragma unroll
        for (int m = 0; m < FM; ++m) {
            int r = wr * FM * 16 + m * 16 + l16;
            #pragma unroll
            for (int hf = 0; hf < 2; ++hf) {
                int cs = (hf * 4 + l4) ^ (r & 7);    // swizzled read
                af[m][hf] = *(const short8v*)&As[cur][r * BK + cs * 8];
            }
        }
        #pragma unroll
        for (int j = 0; j < FN; ++j) {
            int r = wc * FN * 16 + j * 16 + l16;
            #pragma unroll
            for (int hf = 0; hf < 2; ++hf) {
                int cs = (hf * 4 + l4) ^ (r & 7);
                bf[j][hf] = *(const short8v*)&Bs[cur][r * BK + cs * 8];
            }
        }
        __builtin_amdgcn_s_setprio(1);
        #pragma unroll
        for (int hf = 0; hf < 2; ++hf)
            #pragma unroll
            for (int m = 0; m < FM; ++m)
                #pragma unroll
                for (int j = 0; j < FN; ++j)
                    acc[m][j] = __builtin_amdgcn_mfma_f32_16x16x32_bf16(
                        af[m][hf], bf[j][hf], acc[m][j], 0, 0, 0);
        __builtin_amdgcn_s_setprio(0);
        __builtin_amdgcn_sched_barrier(0);
        __builtin_amdgcn_s_barrier();
        asm volatile("" ::: "memory");
        if (t + 2 < nt) stage(cur, (t + 2) * BK);   // reuse just-freed buffer
    }

    #pragma unroll
    for (int m = 0; m < FM; ++m) {
        #pragma unroll
        for (int j = 0; j < FN; ++j) {
            const int row0 = brow + wr * FM * 16 + m * 16 + l4 * 4;
            const int col  = bcol + wc * FN * 16 + j * 16 + l16;
            float vv[4];
            #pragma unroll
            for (int q2 = 0; q2 < 4; ++q2) {
                size_t idx = (size_t)(row0 + q2) * N + col;
                float a0 = acc[m][j][q2];
                float v = alpha * a0;
                float dv = 0.f, dbv = 0.f;
                if (D)  { dv = D[idx]; v = fmaf(beta, dv, v); }
                if (D2) v = fmaf(g2, D2[idx], v);
                if (Db) { dbv = b2f(Db[idx]); v = fmaf(g3, dbv, v); }
                vv[q2] = v;
                if (C)  C[idx] = v;
                if (Cb) Cb[idx] = f2b(v);
                if (Cb2) {
                    float v2 = pa * a0;
                    if (D)  v2 = fmaf(pb, dv, v2);
                    if (Db) v2 = fmaf(pc, dbv, v2);
                    Cb2[idx] = f2b(v2);
                }
                if (Cb3) {
                    float v3 = qa * a0;
                    if (D)  v3 = fmaf(qb, dv, v3);
                    if (Db) v3 = fmaf(qc, dbv, v3);
                    Cb3[idx] = f2b(v3);
                }
            }
            if (CbT) {
                ushort4 t4;
                t4.x = f2b(vv[0]); t4.y = f2b(vv[1]);
                t4.z = f2b(vv[2]); t4.w = f2b(vv[3]);
                *reinterpret_cast<ushort4*>(&CbT[(size_t)col * M + row0]) = t4;
            }
        }
    }
}

// ---------------- host orchestration ----------------

extern "C" void kernel_launch(void* const* d_in, const int* in_sizes, int n_in,
                              void* d_out, int out_size, void* d_ws, size_t ws_size,
                              hipStream_t stream)
{
    const float* x     = (const float*)d_in[0];   // [n, h]
    const float* x0    = (const float*)d_in[1];   // [n, h]
    const float* adj   = (const float*)d_in[2];   // [n, n]
    const float* alpha = (const float*)d_in[3];   // [n]
    const float* w     = (const float*)d_in[4];   // [h, h]
    const float* dvec  = (const float*)d_in[5];   // [h]

    const int n = in_sizes[3];      // 2048
    const int h = in_sizes[5];      // 1024
    const size_t MB = 1u << 20;
    char* ws = (char*)d_ws;

    typedef unsigned short u16;
    // ---- workspace (MiB offsets, phase-overlaid; peak 66 MiB) ----
    // Phase A
    float* Xs    = (float*)(ws + 0 * MB);    // 16, dies after A2
    u16*   XAb   = (u16*)(ws + 16 * MB);     // 8,  dies after A1
    u16*   XAT   = (u16*)(ws + 24 * MB);     // 8,  dies after A2
    u16*   T2b   = (u16*)(ws + 32 * MB);     // 8,  dies after A2
    u16*   Mah   = (u16*)(ws + 40 * MB);     // 8,  dies after v-GEMM
    u16*   Pmb   = (u16*)(ws + 48 * MB);     // 8,  dies after F-GEMM
    u16*   M3ah  = (u16*)(ws + 56 * MB);     // 8,  persists (scan)
    // Phase B (over [0,40), all phase-A temps dead)
    u16*   Eb_   = (u16*)(ws + 0 * MB);      // 2
    u16*   Edb   = (u16*)(ws + 2 * MB);      // 2
    float* Edf   = (float*)(ws + 4 * MB);    // 4
    float* R     = (float*)(ws + 8 * MB);    // 4
    float* XBf   = (float*)(ws + 12 * MB);   // 4
    u16*   XBb   = (u16*)(ws + 16 * MB);     // 2
    u16*   XBT   = (u16*)(ws + 18 * MB);     // 2
    u16*   t2b   = (u16*)(ws + 20 * MB);     // 2
    u16*   t3b   = (u16*)(ws + 22 * MB);     // 2
    float* S3    = (float*)(ws + 24 * MB);   // 4
    u16*   MbT   = (u16*)(ws + 28 * MB);     // 2, persists (forcing chain)
    u16*   Mbb   = (u16*)(ws + 30 * MB);     // 2, dies after B6
    float* Mb2Tf = (float*)(ws + 32 * MB);   // 4, dies after B6
    u16*   Mb2Tb = (u16*)(ws + 36 * MB);     // 2, dies after B6
    u16*   M3bTb = (u16*)(ws + 64 * MB);     // 2, persists (scan)
    // Phase C (forcing chain + scan)
    u16*   x0T   = (u16*)(ws + 0 * MB);      // 4
    float* Ff    = (float*)(ws + 4 * MB);    // 8, dies after F3
    u16*   FTb   = (u16*)(ws + 12 * MB);     // 4, dies after u
    float* uf    = (float*)(ws + 16 * MB);   // 8, dies after F2
    u16*   ub    = (u16*)(ws + 24 * MB);     // 4, dies after F2
    float* F2f   = (float*)(ws + 32 * MB);   // 8, dies after v
    u16*   F2Tb  = (u16*)(ws + 12 * MB);     // 4 (over FTb), dies after v
    float* vf    = (float*)(ws + 16 * MB);   // 8 (over uf), dies after F3
    u16*   vb    = (u16*)(ws + 24 * MB);     // 4 (over ub), dies after F3
    float* F3f   = (float*)(ws + 40 * MB);   // 8 (over Mah, dead), persists
    u16*   zt    = (u16*)(ws + 48 * MB);     // 4 (over Pmb, dead)
    float* tf    = (float*)(ws + 0 * MB);    // 8 (scan)
    u16*   tb16  = (u16*)(ws + 8 * MB);      // 4 (scan)
    float* za    = (float*)(ws + 16 * MB);   // 8 (scan, over vf dead)

    const dim3 blk(256);
    const dim3 gNN(n / 64, n / 128);   // 32x16 = 512 blocks (2/CU), tile 128x64
    const dim3 gHN(h / 64, n / 128);   // 16x16 = 256 blocks, tile 128x64
    const dim3 gHH(h / 64, h / 64);    // 16x16 = 256 blocks, tile 64x64
    const float dt = 0.1f;
    const u16* nu16 = nullptr;
    const float* nf32 = nullptr;

    // ===== Phase A: Mah = e^X-I, Pmb = phi1-I, M3ah = e^{3X}-I (order 3) =====
    k_build_A<<<dim3(n / 256, n), blk, 0, stream>>>(adj, alpha, Xs, XAb, n, 0.5f * dt);
    k_tsplit<<<dim3(n / 32, n / 32), dim3(32, 8), 0, stream>>>(Xs, XAT, n, n);
    // A1: T2b = bf16(X^2)
    gemm_bf16<4, 2, 2><<<gNN, blk, 0, stream>>>(
        XAb, XAT, nullptr, T2b, nullptr, nullptr, nullptr, nf32, nf32, nu16,
        n, n, n, 1.f, 0.f, 0.f, 0.f, 0.f, 0.f, 0.f, 0.f, 0.f, 0.f);
    // A2: acc = X^2 @ X = X^3
    //   Ma  =   X +     X^2/2 +    X^3/6   -> Mah  (Cb)
    //   Pm  =  X/2 +    X^2/6 +    X^3/24  -> Pmb  (Cb2)
    //   M3a =  3X +  4.5 X^2  + 4.5 X^3    -> M3ah (Cb3)
    gemm_bf16<4, 2, 2><<<gNN, blk, 0, stream>>>(
        T2b, XAT, nullptr, Mah, Pmb, M3ah, nullptr, Xs, nf32, T2b,
        n, n, n, 1.f / 6.f, 1.f, 0.f, 0.5f,
        1.f / 24.f, 0.5f, 1.f / 6.f, 4.5f, 3.f, 4.5f);

    // ===== Phase B: Mb = e^{dtB}-I (order 4), M3bT = (3Mb+3Mb^2+Mb^3)^T =====
    k_build_EW<<<dim3(h / 256, h), blk, 0, stream>>>(w, dvec, Eb_, Edb, Edf, h);
    k_build_R<<<dim3(h / 32, h / 32), dim3(32, 8), 0, stream>>>(Edf, dvec, R, h, dt);
    // B1: XB = dt*(Ed @ E^T) + R
    gemm_bf16<2, 2, 4><<<gHH, blk, 0, stream>>>(
        Edb, Eb_, XBf, XBb, nullptr, nullptr, XBT, R, nf32, nu16,
        h, h, h, dt, 1.f, 0.f, 0.f, 0.f, 0.f, 0.f, 0.f, 0.f, 0.f);
    // B2: t2b = bf16(XB^2/2)
    gemm_bf16<2, 2, 4><<<gHH, blk, 0, stream>>>(
        XBb, XBT, nullptr, t2b, nullptr, nullptr, nullptr, nf32, nf32, nu16,
        h, h, h, 0.5f, 0.f, 0.f, 0.f, 0.f, 0.f, 0.f, 0.f, 0.f, 0.f);
    // B3: acc = t2@XB = XB^3/2 ; S3 = acc/3 + XBf + t2 ; t3b = bf16(acc/3)
    gemm_bf16<2, 2, 4><<<gHH, blk, 0, stream>>>(
        t2b, XBT, S3, nullptr, t3b, nullptr, nullptr, XBf, nf32, t2b,
        h, h, h, 1.f / 3.f, 1.f, 0.f, 1.f, 1.f / 3.f, 0.f, 0.f, 0.f, 0.f, 0.f);
    // B4: Mb = acc/4 + S3 -> MbT (CbT) + Mbb (Cb)
    gemm_bf16<2, 2, 4><<<gHH, blk, 0, stream>>>(
        t3b, XBT, nullptr, Mbb, nullptr, nullptr, MbT, S3, nf32, nu16,
        h, h, h, 0.25f, 1.f, 0.f, 0.f, 0.f, 0.f, 0.f, 0.f, 0.f, 0.f);
    // B5: Mb2T = (Mb^2)^T = MbT @ [BT=Mbb]  -> f32 + bf16
    gemm_bf16<2, 2, 4><<<gHH, blk, 0, stream>>>(
        MbT, Mbb, Mb2Tf, Mb2Tb, nullptr, nullptr, nullptr, nf32, nf32, nu16,
        h, h, h, 1.f, 0.f, 0.f, 0.f, 0.f, 0.f, 0.f, 0.f, 0.f, 0.f);
    // B6: M3bT = Mb2T@Mb^T + 3*Mb2T + 3*MbT = (Mb^3 + 3Mb^2 + 3Mb)^T
    gemm_bf16<2, 2, 4><<<gHH, blk, 0, stream>>>(
        Mb2Tb, Mbb, nullptr, M3bTb, nullptr, nullptr, nullptr, Mb2Tf, nf32, MbT,
        h, h, h, 1.f, 3.f, 0.f, 3.f, 0.f, 0.f, 0.f, 0.f, 0.f, 0.f);

    // ===== Phase C: forcing chain F -> F2 -> F3 =====
    k_tsplit<<<dim3(h / 32, n / 32), dim3(32, 8), 0, stream>>>(x0, x0T, n, h);
    // F = dt*(Pm@x0) + dt*x0 -> Ff (f32) + FTb (bf16 T)
    gemm_bf16<4, 2, 2><<<gHN, blk, 0, stream>>>(
        Pmb, x0T, Ff, nullptr, nullptr, nullptr, FTb, x0, nf32, nu16,
        n, h, n, dt, dt, 0.f, 0.f, 0.f, 0.f, 0.f, 0.f, 0.f, 0.f);
    // u = Ma@F + F -> uf + ub
    gemm_bf16<4, 2, 2><<<gHN, blk, 0, stream>>>(
        Mah, FTb, uf, ub, nullptr, nullptr, nullptr, Ff, nf32, nu16,
        n, h, n, 1.f, 1.f, 0.f, 0.f, 0.f, 0.f, 0.f, 0.f, 0.f, 0.f);
    // F2 = u@Mb + u + F -> F2f + F2Tb
    gemm_bf16<4, 2, 2><<<gHN, blk, 0, stream>>>(
        ub, MbT, F2f, nullptr, nullptr, nullptr, F2Tb, uf, Ff, nu16,
        n, h, h, 1.f, 1.f, 1.f, 0.f, 0.f, 0.f, 0.f, 0.f, 0.f, 0.f);
    // v = Ma@F2 + F2 -> vf + vb
    gemm_bf16<4, 2, 2><<<gHN, blk, 0, stream>>>(
        Mah, F2Tb, vf, vb, nullptr, nullptr, nullptr, F2f, nf32, nu16,
        n, h, n, 1.f, 1.f, 0.f, 0.f, 0.f, 0.f, 0.f, 0.f, 0.f, 0.f);
    // F3 = v@Mb + v + F -> F3f
    gemm_bf16<4, 2, 2><<<gHN, blk, 0, stream>>>(
        vb, MbT, F3f, nullptr, nullptr, nullptr, nullptr, vf, Ff, nu16,
        n, h, h, 1.f, 1.f, 1.f, 0.f, 0.f, 0.f, 0.f, 0.f, 0.f, 0.f);

    // ===== scan: 3 triple-steps (total 9 = int(1.0 // 0.1)) =====
    k_tsplit<<<dim3(h / 32, n / 32), dim3(32, 8), 0, stream>>>(x, zt, n, h);
    const float* zf = x;
    for (int s = 0; s < 3; ++s) {
        // G1: tf = M3a@z + z ; tb16 = bf16(tf)
        gemm_bf16<4, 2, 2><<<gHN, blk, 0, stream>>>(
            M3ah, zt, tf, tb16, nullptr, nullptr, nullptr, zf, nf32, nu16,
            n, h, n, 1.f, 1.f, 0.f, 0.f, 0.f, 0.f, 0.f, 0.f, 0.f, 0.f);
        // G2: z''' = t@M3b + t + F3 -> za (f32) + zt (bf16 T) [last: d_out]
        float* zout = (s == 2) ? (float*)d_out : za;
        gemm_bf16<4, 2, 2><<<gHN, blk, 0, stream>>>(
            tb16, M3bTb, zout, nullptr, nullptr, nullptr, (s == 2) ? nullptr : zt,
            tf, F3f, nu16,
            n, h, h, 1.f, 1.f, 1.f, 0.f, 0.f, 0.f, 0.f, 0.f, 0.f, 0.f);
        zf = za;
    }
}

// Round 10
// 428.488 us; speedup vs baseline: 1.2903x; 1.2903x over previous
//
#include <hip/hip_runtime.h>

typedef __attribute__((ext_vector_type(8))) short short8v;
typedef __attribute__((ext_vector_type(4))) float f32x4;

typedef const __attribute__((address_space(1))) void gvoid_t;
typedef __attribute__((address_space(3))) void svoid_t;

__device__ __forceinline__ unsigned short f2b(float f) {
    unsigned u = __float_as_uint(f);
    unsigned r = (u + 0x7fffu + ((u >> 16) & 1u)) >> 16;
    return (unsigned short)r;
}
__device__ __forceinline__ float b2f(unsigned short h) {
    return __uint_as_float((unsigned)h << 16);
}

// ---------------- elementwise / setup kernels ----------------

__global__ void k_build_A(const float* __restrict__ adj,
                          const float* __restrict__ alpha,
                          float* __restrict__ Xs, unsigned short* __restrict__ Xb,
                          int n, float scale)
{
    int j = blockIdx.x * 256 + threadIdx.x;
    int i = blockIdx.y;
    if (j >= n) return;
    size_t idx = (size_t)i * n + j;
    float s = 1.f / (1.f + expf(-alpha[i]));
    float v = scale * s * (adj[idx] - (i == j ? 1.f : 0.f));
    Xs[idx] = v;
    Xb[idx] = f2b(v);
}

__global__ void k_build_EW(const float* __restrict__ w,
                           const float* __restrict__ d,
                           unsigned short* __restrict__ Eb,
                           unsigned short* __restrict__ Edb,
                           float* __restrict__ Edf, int h)
{
    int j = blockIdx.x * 256 + threadIdx.x;
    int i = blockIdx.y;
    if (j >= h) return;
    size_t idx = (size_t)i * h + j;
    float e = w[idx] - (i == j ? 1.f : 0.f);
    float dc = fminf(fmaxf(d[j], 0.f), 1.f);
    Eb[idx] = f2b(e);
    float ed = e * dc;
    Edb[idx] = f2b(ed);
    Edf[idx] = ed;
}

__global__ void k_build_R(const float* __restrict__ Ed,
                          const float* __restrict__ d,
                          float* __restrict__ R, int h, float dt)
{
    __shared__ float tile[32][33];
    int bx = blockIdx.x * 32, by = blockIdx.y * 32;
    int tx = threadIdx.x, ty = threadIdx.y;
    #pragma unroll
    for (int r = 0; r < 32; r += 8)
        tile[ty + r][tx] = Ed[(size_t)(bx + ty + r) * h + by + tx];
    __syncthreads();
    #pragma unroll
    for (int r = 0; r < 32; r += 8) {
        int i = by + ty + r, j = bx + tx;
        float v = Ed[(size_t)i * h + j] + tile[tx][ty + r];
        if (i == j) v += fminf(fmaxf(d[i], 0.f), 1.f) - 1.f;
        R[(size_t)i * h + j] = dt * v;
    }
}

__global__ void k_tsplit(const float* __restrict__ in,
                         unsigned short* __restrict__ outT, int R, int C)
{
    __shared__ float tile[32][33];
    int bx = blockIdx.x * 32, by = blockIdx.y * 32;
    int tx = threadIdx.x, ty = threadIdx.y;
    #pragma unroll
    for (int r = 0; r < 32; r += 8)
        tile[ty + r][tx] = in[(size_t)(by + ty + r) * C + bx + tx];
    __syncthreads();
    #pragma unroll
    for (int r = 0; r < 32; r += 8)
        outT[(size_t)(bx + ty + r) * R + by + tx] = f2b(tile[tx][ty + r]);
}

// ------- bf16 MFMA GEMM: BM=FM*32 x BN=FN*32 tile, BK=64, 2-buffer ----------
// counted-vmcnt pipeline (R8-proven config: FM=FN=2, 32KB LDS, 4 blocks/CU).
// acc = A @ B  (A: MxK bf16 row-major; BT: NxK bf16 row-major = B transposed)
// v  = alpha*acc + beta*D + g2*D2 + g3*b2f(Db) -> C (f32), Cb (bf16), CbT ([N][M] bf16)
// v2 = pa*acc + pb*D + pc*b2f(Db)              -> Cb2 (bf16)
// v3 = qa*acc + qb*D + qc*b2f(Db)              -> Cb3 (bf16)
// 256 threads = 4 waves (2x2), per-wave (FM*16)x(FN*16).
// LDS: linear global_load_lds dest; XOR-swizzled source + swizzled ds_read
// (rule #21 both-sides) -> 0 bank conflicts (R5-R9 verified).
// XCD row-stripe swizzle: XCD q owns gridDim.y/8 row-blocks x all cols
// (A-panel L2-resident per XCD). Requires gridDim.y % 8 == 0.

template<int FM, int FN, int MW>
__global__ __launch_bounds__(256, MW)
void gemm_bf16(const unsigned short* __restrict__ A,
               const unsigned short* __restrict__ BT,
               float* __restrict__ C,
               unsigned short* __restrict__ Cb,
               unsigned short* __restrict__ Cb2,
               unsigned short* __restrict__ Cb3,
               unsigned short* __restrict__ CbT,
               const float* __restrict__ D,
               const float* __restrict__ D2,
               const unsigned short* __restrict__ Db,
               int M, int N, int K,
               float alpha, float beta, float g2, float g3,
               float pa, float pb, float pc,
               float qa, float qb, float qc)
{
    constexpr int BM = FM * 32, BN = FN * 32, BK = 64;
    constexpr int AIT = BM * BK / (8 * 256);   // 16B chunks per thread (A)
    constexpr int BIT = BN * BK / (8 * 256);
    constexpr int LPT = AIT + BIT;
    __shared__ unsigned short As[2][BM * BK];
    __shared__ unsigned short Bs[2][BN * BK];

    // XCD row-stripe swizzle (requires gridDim.y % 8 == 0)
    int bid = blockIdx.y * gridDim.x + blockIdx.x;
    int rpx = gridDim.y >> 3;
    int q = bid & 7, c = bid >> 3;
    int by = q * rpx + (c % rpx);
    int bx = c / rpx;

    const int tid  = threadIdx.x;
    const int lane = tid & 63;
    const int wave = tid >> 6;
    const int wr = wave >> 1, wc = wave & 1;   // 2 x 2 wave grid
    const int l16 = lane & 15, l4 = lane >> 4;
    const int brow = by * BM, bcol = bx * BN;

    f32x4 acc[FM][FN];
    #pragma unroll
    for (int m = 0; m < FM; ++m)
        #pragma unroll
        for (int j = 0; j < FN; ++j)
            acc[m][j] = (f32x4){0.f, 0.f, 0.f, 0.f};

    const unsigned short* Ab = A + (size_t)brow * K;
    const unsigned short* Bb = BT + (size_t)bcol * K;
    const int nt = K / BK;

    auto stage = [&](int b, int k0) {
        #pragma unroll
        for (int it = 0; it < AIT; ++it) {
            int cb = it * 256 + wave * 64;          // wave-uniform chunk base
            int ch = cb + lane;
            int r = ch >> 3, cc = ch & 7;
            int cs = cc ^ (r & 7);                  // inverse-swizzled source
            __builtin_amdgcn_global_load_lds(
                (gvoid_t*)(Ab + (size_t)r * K + k0 + cs * 8),
                (svoid_t*)(&As[b][cb * 8]), 16, 0, 0);
        }
        #pragma unroll
        for (int it = 0; it < BIT; ++it) {
            int cb = it * 256 + wave * 64;
            int ch = cb + lane;
            int r = ch >> 3, cc = ch & 7;
            int cs = cc ^ (r & 7);
            __builtin_amdgcn_global_load_lds(
                (gvoid_t*)(Bb + (size_t)r * K + k0 + cs * 8),
                (svoid_t*)(&Bs[b][cb * 8]), 16, 0, 0);
        }
    };

    stage(0, 0);
    stage(1, BK);

    for (int t = 0; t < nt; ++t) {
        const int cur = t & 1;
        if (t + 1 < nt) {
            asm volatile("s_waitcnt vmcnt(%0)" :: "i"(LPT) : "memory");
        } else {
            asm volatile("s_waitcnt vmcnt(0)" ::: "memory");
        }
        __builtin_amdgcn_s_barrier();
        asm volatile("" ::: "memory");
        __builtin_amdgcn_sched_barrier(0);

        short8v af[FM][2], bf[FN][2];
        #pragma unroll
        for (int m = 0; m < FM; ++m) {
            int r = wr * FM * 16 + m * 16 + l16;
            #pragma unroll
            for (int hf = 0; hf < 2; ++hf) {
                int cs = (hf * 4 + l4) ^ (r & 7);    // swizzled read
                af[m][hf] = *(const short8v*)&As[cur][r * BK + cs * 8];
            }
        }
        #pragma unroll
        for (int j = 0; j < FN; ++j) {
            int r = wc * FN * 16 + j * 16 + l16;
            #pragma unroll
            for (int hf = 0; hf < 2; ++hf) {
                int cs = (hf * 4 + l4) ^ (r & 7);
                bf[j][hf] = *(const short8v*)&Bs[cur][r * BK + cs * 8];
            }
        }
        __builtin_amdgcn_s_setprio(1);
        #pragma unroll
        for (int hf = 0; hf < 2; ++hf)
            #pragma unroll
            for (int m = 0; m < FM; ++m)
                #pragma unroll
                for (int j = 0; j < FN; ++j)
                    acc[m][j] = __builtin_amdgcn_mfma_f32_16x16x32_bf16(
                        af[m][hf], bf[j][hf], acc[m][j], 0, 0, 0);
        __builtin_amdgcn_s_setprio(0);
        __builtin_amdgcn_sched_barrier(0);
        __builtin_amdgcn_s_barrier();
        asm volatile("" ::: "memory");
        if (t + 2 < nt) stage(cur, (t + 2) * BK);   // reuse just-freed buffer
    }

    #pragma unroll
    for (int m = 0; m < FM; ++m) {
        #pragma unroll
        for (int j = 0; j < FN; ++j) {
            const int row0 = brow + wr * FM * 16 + m * 16 + l4 * 4;
            const int col  = bcol + wc * FN * 16 + j * 16 + l16;
            float vv[4];
            #pragma unroll
            for (int q2 = 0; q2 < 4; ++q2) {
                size_t idx = (size_t)(row0 + q2) * N + col;
                float a0 = acc[m][j][q2];
                float v = alpha * a0;
                float dv = 0.f, dbv = 0.f;
                if (D)  { dv = D[idx]; v = fmaf(beta, dv, v); }
                if (D2) v = fmaf(g2, D2[idx], v);
                if (Db) { dbv = b2f(Db[idx]); v = fmaf(g3, dbv, v); }
                vv[q2] = v;
                if (C)  C[idx] = v;
                if (Cb) Cb[idx] = f2b(v);
                if (Cb2) {
                    float v2 = pa * a0;
                    if (D)  v2 = fmaf(pb, dv, v2);
                    if (Db) v2 = fmaf(pc, dbv, v2);
                    Cb2[idx] = f2b(v2);
                }
                if (Cb3) {
                    float v3 = qa * a0;
                    if (D)  v3 = fmaf(qb, dv, v3);
                    if (Db) v3 = fmaf(qc, dbv, v3);
                    Cb3[idx] = f2b(v3);
                }
            }
            if (CbT) {
                ushort4 t4;
                t4.x = f2b(vv[0]); t4.y = f2b(vv[1]);
                t4.z = f2b(vv[2]); t4.w = f2b(vv[3]);
                *reinterpret_cast<ushort4*>(&CbT[(size_t)col * M + row0]) = t4;
            }
        }
    }
}

// ---------------- host orchestration ----------------

extern "C" void kernel_launch(void* const* d_in, const int* in_sizes, int n_in,
                              void* d_out, int out_size, void* d_ws, size_t ws_size,
                              hipStream_t stream)
{
    const float* x     = (const float*)d_in[0];   // [n, h]
    const float* x0    = (const float*)d_in[1];   // [n, h]
    const float* adj   = (const float*)d_in[2];   // [n, n]
    const float* alpha = (const float*)d_in[3];   // [n]
    const float* w     = (const float*)d_in[4];   // [h, h]
    const float* dvec  = (const float*)d_in[5];   // [h]

    const int n = in_sizes[3];      // 2048
    const int h = in_sizes[5];      // 1024
    const size_t MB = 1u << 20;
    char* ws = (char*)d_ws;

    typedef unsigned short u16;
    // ---- workspace (MiB offsets, phase-overlaid; peak 66 MiB) ----
    // Phase A
    float* Xs    = (float*)(ws + 0 * MB);    // 16, dies after A2
    u16*   XAb   = (u16*)(ws + 16 * MB);     // 8,  dies after A1
    u16*   XAT   = (u16*)(ws + 24 * MB);     // 8,  dies after A2
    u16*   T2b   = (u16*)(ws + 32 * MB);     // 8,  dies after A2
    u16*   Mah   = (u16*)(ws + 40 * MB);     // 8,  dies after v-GEMM
    u16*   Pmb   = (u16*)(ws + 48 * MB);     // 8,  dies after F-GEMM
    u16*   M3ah  = (u16*)(ws + 56 * MB);     // 8,  persists (scan)
    // Phase B (over [0,40), all phase-A temps dead)
    u16*   Eb_   = (u16*)(ws + 0 * MB);      // 2
    u16*   Edb   = (u16*)(ws + 2 * MB);      // 2
    float* Edf   = (float*)(ws + 4 * MB);    // 4
    float* R     = (float*)(ws + 8 * MB);    // 4
    float* XBf   = (float*)(ws + 12 * MB);   // 4
    u16*   XBb   = (u16*)(ws + 16 * MB);     // 2
    u16*   XBT   = (u16*)(ws + 18 * MB);     // 2
    u16*   t2b   = (u16*)(ws + 20 * MB);     // 2
    u16*   t3b   = (u16*)(ws + 22 * MB);     // 2
    float* S3    = (float*)(ws + 24 * MB);   // 4
    u16*   MbT   = (u16*)(ws + 28 * MB);     // 2, persists (forcing chain)
    u16*   Mbb   = (u16*)(ws + 30 * MB);     // 2, dies after B6
    float* Mb2Tf = (float*)(ws + 32 * MB);   // 4, dies after B6
    u16*   Mb2Tb = (u16*)(ws + 36 * MB);     // 2, dies after B6
    u16*   M3bTb = (u16*)(ws + 64 * MB);     // 2, persists (scan)
    // Phase C (forcing chain + scan)
    u16*   x0T   = (u16*)(ws + 0 * MB);      // 4
    float* Ff    = (float*)(ws + 4 * MB);    // 8, dies after F3
    u16*   FTb   = (u16*)(ws + 12 * MB);     // 4, dies after u
    float* uf    = (float*)(ws + 16 * MB);   // 8, dies after F2
    u16*   ub    = (u16*)(ws + 24 * MB);     // 4, dies after F2
    float* F2f   = (float*)(ws + 32 * MB);   // 8, dies after v
    u16*   F2Tb  = (u16*)(ws + 12 * MB);     // 4 (over FTb), dies after v
    float* vf    = (float*)(ws + 16 * MB);   // 8 (over uf), dies after F3
    u16*   vb    = (u16*)(ws + 24 * MB);     // 4 (over ub), dies after F3
    float* F3f   = (float*)(ws + 40 * MB);   // 8 (over Mah, dead), persists
    u16*   zt    = (u16*)(ws + 48 * MB);     // 4 (over Pmb, dead)
    float* tf    = (float*)(ws + 0 * MB);    // 8 (scan)
    u16*   tb16  = (u16*)(ws + 8 * MB);      // 4 (scan)
    float* za    = (float*)(ws + 16 * MB);   // 8 (scan, over vf dead)

    const dim3 blk(256);
    const dim3 gNN(n / 64, n / 64);    // 32x32 = 1024 blocks (4/CU), 64x64 tile
    const dim3 gHN(h / 64, n / 64);    // 16x32 = 512 blocks  (2/CU), 64x64 tile
    const dim3 gHH(h / 64, h / 32);    // 16x32 = 512 blocks  (2/CU), 32x64 tile
    const float dt = 0.1f;
    const u16* nu16 = nullptr;
    const float* nf32 = nullptr;

    // ===== Phase A: Mah = e^X-I, Pmb = phi1-I, M3ah = e^{3X}-I (order 3) =====
    k_build_A<<<dim3(n / 256, n), blk, 0, stream>>>(adj, alpha, Xs, XAb, n, 0.5f * dt);
    k_tsplit<<<dim3(n / 32, n / 32), dim3(32, 8), 0, stream>>>(Xs, XAT, n, n);
    // A1: T2b = bf16(X^2)
    gemm_bf16<2, 2, 4><<<gNN, blk, 0, stream>>>(
        XAb, XAT, nullptr, T2b, nullptr, nullptr, nullptr, nf32, nf32, nu16,
        n, n, n, 1.f, 0.f, 0.f, 0.f, 0.f, 0.f, 0.f, 0.f, 0.f, 0.f);
    // A2: acc = X^2 @ X = X^3
    //   Ma  =   X +     X^2/2 +    X^3/6   -> Mah  (Cb)
    //   Pm  =  X/2 +    X^2/6 +    X^3/24  -> Pmb  (Cb2)
    //   M3a =  3X +  4.5 X^2  + 4.5 X^3    -> M3ah (Cb3)
    gemm_bf16<2, 2, 4><<<gNN, blk, 0, stream>>>(
        T2b, XAT, nullptr, Mah, Pmb, M3ah, nullptr, Xs, nf32, T2b,
        n, n, n, 1.f / 6.f, 1.f, 0.f, 0.5f,
        1.f / 24.f, 0.5f, 1.f / 6.f, 4.5f, 3.f, 4.5f);

    // ===== Phase B: Mb = e^{dtB}-I (order 4), M3bT = (3Mb+3Mb^2+Mb^3)^T =====
    k_build_EW<<<dim3(h / 256, h), blk, 0, stream>>>(w, dvec, Eb_, Edb, Edf, h);
    k_build_R<<<dim3(h / 32, h / 32), dim3(32, 8), 0, stream>>>(Edf, dvec, R, h, dt);
    // B1: XB = dt*(Ed @ E^T) + R
    gemm_bf16<1, 2, 4><<<gHH, blk, 0, stream>>>(
        Edb, Eb_, XBf, XBb, nullptr, nullptr, XBT, R, nf32, nu16,
        h, h, h, dt, 1.f, 0.f, 0.f, 0.f, 0.f, 0.f, 0.f, 0.f, 0.f);
    // B2: t2b = bf16(XB^2/2)
    gemm_bf16<1, 2, 4><<<gHH, blk, 0, stream>>>(
        XBb, XBT, nullptr, t2b, nullptr, nullptr, nullptr, nf32, nf32, nu16,
        h, h, h, 0.5f, 0.f, 0.f, 0.f, 0.f, 0.f, 0.f, 0.f, 0.f, 0.f);
    // B3: acc = t2@XB = XB^3/2 ; S3 = acc/3 + XBf + t2 ; t3b = bf16(acc/3)
    gemm_bf16<1, 2, 4><<<gHH, blk, 0, stream>>>(
        t2b, XBT, S3, nullptr, t3b, nullptr, nullptr, XBf, nf32, t2b,
        h, h, h, 1.f / 3.f, 1.f, 0.f, 1.f, 1.f / 3.f, 0.f, 0.f, 0.f, 0.f, 0.f);
    // B4: Mb = acc/4 + S3 -> MbT (CbT) + Mbb (Cb)
    gemm_bf16<1, 2, 4><<<gHH, blk, 0, stream>>>(
        t3b, XBT, nullptr, Mbb, nullptr, nullptr, MbT, S3, nf32, nu16,
        h, h, h, 0.25f, 1.f, 0.f, 0.f, 0.f, 0.f, 0.f, 0.f, 0.f, 0.f);
    // B5: Mb2T = (Mb^2)^T = MbT @ [BT=Mbb]  -> f32 + bf16
    gemm_bf16<1, 2, 4><<<gHH, blk, 0, stream>>>(
        MbT, Mbb, Mb2Tf, Mb2Tb, nullptr, nullptr, nullptr, nf32, nf32, nu16,
        h, h, h, 1.f, 0.f, 0.f, 0.f, 0.f, 0.f, 0.f, 0.f, 0.f, 0.f);
    // B6: M3bT = Mb2T@Mb^T + 3*Mb2T + 3*MbT = (Mb^3 + 3Mb^2 + 3Mb)^T
    gemm_bf16<1, 2, 4><<<gHH, blk, 0, stream>>>(
        Mb2Tb, Mbb, nullptr, M3bTb, nullptr, nullptr, nullptr, Mb2Tf, nf32, MbT,
        h, h, h, 1.f, 3.f, 0.f, 3.f, 0.f, 0.f, 0.f, 0.f, 0.f, 0.f);

    // ===== Phase C: forcing chain F -> F2 -> F3 =====
    k_tsplit<<<dim3(h / 32, n / 32), dim3(32, 8), 0, stream>>>(x0, x0T, n, h);
    // F = dt*(Pm@x0) + dt*x0 -> Ff (f32) + FTb (bf16 T)
    gemm_bf16<2, 2, 4><<<gHN, blk, 0, stream>>>(
        Pmb, x0T, Ff, nullptr, nullptr, nullptr, FTb, x0, nf32, nu16,
        n, h, n, dt, dt, 0.f, 0.f, 0.f, 0.f, 0.f, 0.f, 0.f, 0.f);
    // u = Ma@F + F -> uf + ub
    gemm_bf16<2, 2, 4><<<gHN, blk, 0, stream>>>(
        Mah, FTb, uf, ub, nullptr, nullptr, nullptr, Ff, nf32, nu16,
        n, h, n, 1.f, 1.f, 0.f, 0.f, 0.f, 0.f, 0.f, 0.f, 0.f, 0.f);
    // F2 = u@Mb + u + F -> F2f + F2Tb
    gemm_bf16<2, 2, 4><<<gHN, blk, 0, stream>>>(
        ub, MbT, F2f, nullptr, nullptr, nullptr, F2Tb, uf, Ff, nu16,
        n, h, h, 1.f, 1.f, 1.f, 0.f, 0.f, 0.f, 0.f, 0.f, 0.f, 0.f);
    // v = Ma@F2 + F2 -> vf + vb
    gemm_bf16<2, 2, 4><<<gHN, blk, 0, stream>>>(
        Mah, F2Tb, vf, vb, nullptr, nullptr, nullptr, F2f, nf32, nu16,
        n, h, n, 1.f, 1.f, 0.f, 0.f, 0.f, 0.f, 0.f, 0.f, 0.f, 0.f);
    // F3 = v@Mb + v + F -> F3f
    gemm_bf16<2, 2, 4><<<gHN, blk, 0, stream>>>(
        vb, MbT, F3f, nullptr, nullptr, nullptr, nullptr, vf, Ff, nu16,
        n, h, h, 1.f, 1.f, 1.f, 0.f, 0.f, 0.f, 0.f, 0.f, 0.f, 0.f);

    // ===== scan: 3 triple-steps (total 9 = int(1.0 // 0.1)) =====
    k_tsplit<<<dim3(h / 32, n / 32), dim3(32, 8), 0, stream>>>(x, zt, n, h);
    const float* zf = x;
    for (int s = 0; s < 3; ++s) {
        // G1: tf = M3a@z + z ; tb16 = bf16(tf)
        gemm_bf16<2, 2, 4><<<gHN, blk, 0, stream>>>(
            M3ah, zt, tf, tb16, nullptr, nullptr, nullptr, zf, nf32, nu16,
            n, h, n, 1.f, 1.f, 0.f, 0.f, 0.f, 0.f, 0.f, 0.f, 0.f, 0.f);
        // G2: z''' = t@M3b + t + F3 -> za (f32) + zt (bf16 T) [last: d_out]
        float* zout = (s == 2) ? (float*)d_out : za;
        gemm_bf16<2, 2, 4><<<gHN, blk, 0, stream>>>(
            tb16, M3bTb, zout, nullptr, nullptr, nullptr, (s == 2) ? nullptr : zt,
            tf, F3f, nu16,
            n, h, h, 1.f, 1.f, 1.f, 0.f, 0.f, 0.f, 0.f, 0.f, 0.f, 0.f);
        zf = za;
    }
}

// Round 11
// 378.335 us; speedup vs baseline: 1.4613x; 1.1326x over previous
//
#include <hip/hip_runtime.h>

typedef __attribute__((ext_vector_type(8))) short short8v;
typedef __attribute__((ext_vector_type(4))) float f32x4;

typedef const __attribute__((address_space(1))) void gvoid_t;
typedef __attribute__((address_space(3))) void svoid_t;

__device__ __forceinline__ unsigned short f2b(float f) {
    unsigned u = __float_as_uint(f);
    unsigned r = (u + 0x7fffu + ((u >> 16) & 1u)) >> 16;
    return (unsigned short)r;
}
__device__ __forceinline__ float b2f(unsigned short h) {
    return __uint_as_float((unsigned)h << 16);
}

// ---------------- elementwise / setup kernels ----------------

__global__ void k_build_A(const float* __restrict__ adj,
                          const float* __restrict__ alpha,
                          float* __restrict__ Xs, unsigned short* __restrict__ Xb,
                          int n, float scale)
{
    int j = blockIdx.x * 256 + threadIdx.x;
    int i = blockIdx.y;
    if (j >= n) return;
    size_t idx = (size_t)i * n + j;
    float s = 1.f / (1.f + expf(-alpha[i]));
    float v = scale * s * (adj[idx] - (i == j ? 1.f : 0.f));
    Xs[idx] = v;
    Xb[idx] = f2b(v);
}

__global__ void k_build_EW(const float* __restrict__ w,
                           const float* __restrict__ d,
                           unsigned short* __restrict__ Eb,
                           unsigned short* __restrict__ Edb,
                           float* __restrict__ Edf, int h)
{
    int j = blockIdx.x * 256 + threadIdx.x;
    int i = blockIdx.y;
    if (j >= h) return;
    size_t idx = (size_t)i * h + j;
    float e = w[idx] - (i == j ? 1.f : 0.f);
    float dc = fminf(fmaxf(d[j], 0.f), 1.f);
    Eb[idx] = f2b(e);
    float ed = e * dc;
    Edb[idx] = f2b(ed);
    Edf[idx] = ed;
}

__global__ void k_build_R(const float* __restrict__ Ed,
                          const float* __restrict__ d,
                          float* __restrict__ R, int h, float dt)
{
    __shared__ float tile[32][33];
    int bx = blockIdx.x * 32, by = blockIdx.y * 32;
    int tx = threadIdx.x, ty = threadIdx.y;
    #pragma unroll
    for (int r = 0; r < 32; r += 8)
        tile[ty + r][tx] = Ed[(size_t)(bx + ty + r) * h + by + tx];
    __syncthreads();
    #pragma unroll
    for (int r = 0; r < 32; r += 8) {
        int i = by + ty + r, j = bx + tx;
        float v = Ed[(size_t)i * h + j] + tile[tx][ty + r];
        if (i == j) v += fminf(fmaxf(d[i], 0.f), 1.f) - 1.f;
        R[(size_t)i * h + j] = dt * v;
    }
}

__global__ void k_tsplit(const float* __restrict__ in,
                         unsigned short* __restrict__ outT, int R, int C)
{
    __shared__ float tile[32][33];
    int bx = blockIdx.x * 32, by = blockIdx.y * 32;
    int tx = threadIdx.x, ty = threadIdx.y;
    #pragma unroll
    for (int r = 0; r < 32; r += 8)
        tile[ty + r][tx] = in[(size_t)(by + ty + r) * C + bx + tx];
    __syncthreads();
    #pragma unroll
    for (int r = 0; r < 32; r += 8)
        outT[(size_t)(bx + ty + r) * R + by + tx] = f2b(tile[tx][ty + r]);
}

// ------- bf16 MFMA GEMM: BM=FM*32 x BN=FN*32 tile, BK=64, 2-buffer ----------
// counted-vmcnt pipeline (R8/R10-proven config: FM=FN=2, 32KB LDS, 4 blocks/CU).
// acc = A @ B  (A: MxK bf16 row-major; BT: NxK bf16 row-major = B transposed)
// v  = alpha*acc + beta*D + g2*D2 + g3*b2f(Db) -> C (f32), Cb (bf16), CbT ([N][M] bf16)
// v2 = pa*acc + pb*D + pc*b2f(Db)              -> C2 (f32), Cb2 (bf16)
// v3 = qa*acc + qb*D + qc*b2f(Db)              -> Cb3 (bf16)
// 256 threads = 4 waves (2x2), per-wave (FM*16)x(FN*16).
// LDS: linear global_load_lds dest; XOR-swizzled source + swizzled ds_read
// (rule #21 both-sides) -> 0 bank conflicts (R5-R10 verified).
// XCD row-stripe swizzle: XCD q owns gridDim.y/8 row-blocks x all cols
// (A-panel L2-resident per XCD). Requires gridDim.y % 8 == 0.

template<int FM, int FN, int MW>
__global__ __launch_bounds__(256, MW)
void gemm_bf16(const unsigned short* __restrict__ A,
               const unsigned short* __restrict__ BT,
               float* __restrict__ C,
               float* __restrict__ C2,
               unsigned short* __restrict__ Cb,
               unsigned short* __restrict__ Cb2,
               unsigned short* __restrict__ Cb3,
               unsigned short* __restrict__ CbT,
               const float* __restrict__ D,
               const float* __restrict__ D2,
               const unsigned short* __restrict__ Db,
               int M, int N, int K,
               float alpha, float beta, float g2, float g3,
               float pa, float pb, float pc,
               float qa, float qb, float qc)
{
    constexpr int BM = FM * 32, BN = FN * 32, BK = 64;
    constexpr int AIT = BM * BK / (8 * 256);   // 16B chunks per thread (A)
    constexpr int BIT = BN * BK / (8 * 256);
    constexpr int LPT = AIT + BIT;
    __shared__ unsigned short As[2][BM * BK];
    __shared__ unsigned short Bs[2][BN * BK];

    // XCD row-stripe swizzle (requires gridDim.y % 8 == 0)
    int bid = blockIdx.y * gridDim.x + blockIdx.x;
    int rpx = gridDim.y >> 3;
    int q = bid & 7, c = bid >> 3;
    int by = q * rpx + (c % rpx);
    int bx = c / rpx;

    const int tid  = threadIdx.x;
    const int lane = tid & 63;
    const int wave = tid >> 6;
    const int wr = wave >> 1, wc = wave & 1;   // 2 x 2 wave grid
    const int l16 = lane & 15, l4 = lane >> 4;
    const int brow = by * BM, bcol = bx * BN;

    f32x4 acc[FM][FN];
    #pragma unroll
    for (int m = 0; m < FM; ++m)
        #pragma unroll
        for (int j = 0; j < FN; ++j)
            acc[m][j] = (f32x4){0.f, 0.f, 0.f, 0.f};

    const unsigned short* Ab = A + (size_t)brow * K;
    const unsigned short* Bb = BT + (size_t)bcol * K;
    const int nt = K / BK;

    auto stage = [&](int b, int k0) {
        #pragma unroll
        for (int it = 0; it < AIT; ++it) {
            int cb = it * 256 + wave * 64;          // wave-uniform chunk base
            int ch = cb + lane;
            int r = ch >> 3, cc = ch & 7;
            int cs = cc ^ (r & 7);                  // inverse-swizzled source
            __builtin_amdgcn_global_load_lds(
                (gvoid_t*)(Ab + (size_t)r * K + k0 + cs * 8),
                (svoid_t*)(&As[b][cb * 8]), 16, 0, 0);
        }
        #pragma unroll
        for (int it = 0; it < BIT; ++it) {
            int cb = it * 256 + wave * 64;
            int ch = cb + lane;
            int r = ch >> 3, cc = ch & 7;
            int cs = cc ^ (r & 7);
            __builtin_amdgcn_global_load_lds(
                (gvoid_t*)(Bb + (size_t)r * K + k0 + cs * 8),
                (svoid_t*)(&Bs[b][cb * 8]), 16, 0, 0);
        }
    };

    stage(0, 0);
    stage(1, BK);

    for (int t = 0; t < nt; ++t) {
        const int cur = t & 1;
        if (t + 1 < nt) {
            asm volatile("s_waitcnt vmcnt(%0)" :: "i"(LPT) : "memory");
        } else {
            asm volatile("s_waitcnt vmcnt(0)" ::: "memory");
        }
        __builtin_amdgcn_s_barrier();
        asm volatile("" ::: "memory");
        __builtin_amdgcn_sched_barrier(0);

        short8v af[FM][2], bf[FN][2];
        #pragma unroll
        for (int m = 0; m < FM; ++m) {
            int r = wr * FM * 16 + m * 16 + l16;
            #pragma unroll
            for (int hf = 0; hf < 2; ++hf) {
                int cs = (hf * 4 + l4) ^ (r & 7);    // swizzled read
                af[m][hf] = *(const short8v*)&As[cur][r * BK + cs * 8];
            }
        }
        #pragma unroll
        for (int j = 0; j < FN; ++j) {
            int r = wc * FN * 16 + j * 16 + l16;
            #pragma unroll
            for (int hf = 0; hf < 2; ++hf) {
                int cs = (hf * 4 + l4) ^ (r & 7);
                bf[j][hf] = *(const short8v*)&Bs[cur][r * BK + cs * 8];
            }
        }
        __builtin_amdgcn_s_setprio(1);
        #pragma unroll
        for (int hf = 0; hf < 2; ++hf)
            #pragma unroll
            for (int m = 0; m < FM; ++m)
                #pragma unroll
                for (int j = 0; j < FN; ++j)
                    acc[m][j] = __builtin_amdgcn_mfma_f32_16x16x32_bf16(
                        af[m][hf], bf[j][hf], acc[m][j], 0, 0, 0);
        __builtin_amdgcn_s_setprio(0);
        __builtin_amdgcn_sched_barrier(0);
        __builtin_amdgcn_s_barrier();
        asm volatile("" ::: "memory");
        if (t + 2 < nt) stage(cur, (t + 2) * BK);   // reuse just-freed buffer
    }

    #pragma unroll
    for (int m = 0; m < FM; ++m) {
        #pragma unroll
        for (int j = 0; j < FN; ++j) {
            const int row0 = brow + wr * FM * 16 + m * 16 + l4 * 4;
            const int col  = bcol + wc * FN * 16 + j * 16 + l16;
            float vv[4];
            #pragma unroll
            for (int q2 = 0; q2 < 4; ++q2) {
                size_t idx = (size_t)(row0 + q2) * N + col;
                float a0 = acc[m][j][q2];
                float v = alpha * a0;
                float dv = 0.f, dbv = 0.f;
                if (D)  { dv = D[idx]; v = fmaf(beta, dv, v); }
                if (D2) v = fmaf(g2, D2[idx], v);
                if (Db) { dbv = b2f(Db[idx]); v = fmaf(g3, dbv, v); }
                vv[q2] = v;
                if (C)  C[idx] = v;
                if (Cb) Cb[idx] = f2b(v);
                if (C2 || Cb2) {
                    float v2 = pa * a0;
                    if (D)  v2 = fmaf(pb, dv, v2);
                    if (Db) v2 = fmaf(pc, dbv, v2);
                    if (C2)  C2[idx] = v2;
                    if (Cb2) Cb2[idx] = f2b(v2);
                }
                if (Cb3) {
                    float v3 = qa * a0;
                    if (D)  v3 = fmaf(qb, dv, v3);
                    if (Db) v3 = fmaf(qc, dbv, v3);
                    Cb3[idx] = f2b(v3);
                }
            }
            if (CbT) {
                ushort4 t4;
                t4.x = f2b(vv[0]); t4.y = f2b(vv[1]);
                t4.z = f2b(vv[2]); t4.w = f2b(vv[3]);
                *reinterpret_cast<ushort4*>(&CbT[(size_t)col * M + row0]) = t4;
            }
        }
    }
}

// ---------------- host orchestration ----------------

extern "C" void kernel_launch(void* const* d_in, const int* in_sizes, int n_in,
                              void* d_out, int out_size, void* d_ws, size_t ws_size,
                              hipStream_t stream)
{
    const float* x     = (const float*)d_in[0];   // [n, h]
    const float* x0    = (const float*)d_in[1];   // [n, h]
    const float* adj   = (const float*)d_in[2];   // [n, n]
    const float* alpha = (const float*)d_in[3];   // [n]
    const float* w     = (const float*)d_in[4];   // [h, h]
    const float* dvec  = (const float*)d_in[5];   // [h]

    const int n = in_sizes[3];      // 2048
    const int h = in_sizes[5];      // 1024
    const size_t MB = 1u << 20;
    char* ws = (char*)d_ws;

    typedef unsigned short u16;
    // ---- workspace (MiB offsets, phase-overlaid; peak 72 MiB) ----
    // Phase A
    float* Xs    = (float*)(ws + 0 * MB);    // 16, dies after A1
    u16*   XAb   = (u16*)(ws + 16 * MB);     // 8,  dies after A1
    u16*   XAT   = (u16*)(ws + 24 * MB);     // 8,  dies after A1
    u16*   Mah   = (u16*)(ws + 32 * MB);     // 8,  dies after v-GEMM
    u16*   Pmb   = (u16*)(ws + 40 * MB);     // 8,  dies after F-GEMM
    u16*   M3ah  = (u16*)(ws + 48 * MB);     // 8,  persists (scan)
    u16*   MbT   = (u16*)(ws + 56 * MB);     // 2,  dies after F3
    u16*   M3bTb = (u16*)(ws + 58 * MB);     // 2,  persists (scan)
    // Phase B (over [0,32); phase-A temps dead)
    u16*   Eb_   = (u16*)(ws + 0 * MB);      // 2
    u16*   Edb   = (u16*)(ws + 2 * MB);      // 2
    float* Edf   = (float*)(ws + 4 * MB);    // 4
    float* R     = (float*)(ws + 8 * MB);    // 4
    float* XBf   = (float*)(ws + 12 * MB);   // 4
    u16*   XBb   = (u16*)(ws + 16 * MB);     // 2
    u16*   XBT   = (u16*)(ws + 18 * MB);     // 2
    float* P2f   = (float*)(ws + 20 * MB);   // 4
    u16*   P2b   = (u16*)(ws + 24 * MB);     // 2
    float* P3f   = (float*)(ws + 26 * MB);   // 4
    u16*   P3b   = (u16*)(ws + 30 * MB);     // 2
    // Phase C (over [0,32) after B; + high slots)
    u16*   x0T   = (u16*)(ws + 0 * MB);      // 4, dies after F
    float* Ff    = (float*)(ws + 4 * MB);    // 8, dies after F3
    u16*   FTb   = (u16*)(ws + 12 * MB);     // 4, dies after u
    float* uf    = (float*)(ws + 16 * MB);   // 8, dies after F2
    u16*   ub    = (u16*)(ws + 24 * MB);     // 4, dies after F2
    float* F2f   = (float*)(ws + 60 * MB);   // 8, dies after v
    u16*   F2Tb  = (u16*)(ws + 12 * MB);     // 4 (over FTb), dies after v
    float* vf    = (float*)(ws + 16 * MB);   // 8 (over uf), dies after F3
    u16*   vb    = (u16*)(ws + 24 * MB);     // 4 (over ub), dies after F3
    float* F3f   = (float*)(ws + 40 * MB);   // 8 (over Pmb, dead), persists
    u16*   zt    = (u16*)(ws + 68 * MB);     // 4, scan state
    float* tf    = (float*)(ws + 0 * MB);    // 8 (scan)
    u16*   tb16  = (u16*)(ws + 8 * MB);      // 4 (scan)
    float* za    = (float*)(ws + 16 * MB);   // 8 (scan, over vf dead)

    const dim3 blk(256);
    const dim3 gNN(n / 64, n / 64);    // 32x32 = 1024 blocks (4/CU), 64x64 tile
    const dim3 gHN(h / 64, n / 64);    // 16x32 = 512 blocks  (2/CU), 64x64 tile
    const dim3 gHH(h / 64, h / 32);    // 16x32 = 512 blocks  (2/CU), 32x64 tile
    const float dt = 0.1f;
    const u16* nu16 = nullptr;
    const float* nf32 = nullptr;

    // ===== Phase A: single n^3 GEMM. acc = X^2; epilogue emits all three =====
    //   Ma  =  X  + X^2/2   -> Mah  (Cb:  alpha=1/2, D=Xs beta=1)
    //   Pm  =  X/2 + X^2/6  -> Pmb  (Cb2: pa=1/6,  pb=1/2)
    //   M3a = 3X + 4.5 X^2  -> M3ah (Cb3: qa=4.5,  qb=3)
    // trunc: Ma ~X^3/6=6.5e-5, M3a ~4.5X^3=1.8e-3 (scan err ~0.01-0.05 << 0.176)
    k_build_A<<<dim3(n / 256, n), blk, 0, stream>>>(adj, alpha, Xs, XAb, n, 0.5f * dt);
    k_tsplit<<<dim3(n / 32, n / 32), dim3(32, 8), 0, stream>>>(Xs, XAT, n, n);
    gemm_bf16<2, 2, 4><<<gNN, blk, 0, stream>>>(
        XAb, XAT, nullptr, nullptr, Mah, Pmb, M3ah, nullptr, Xs, nf32, nu16,
        n, n, n, 0.5f, 1.f, 0.f, 0.f,
        1.f / 6.f, 0.5f, 0.f, 4.5f, 3.f, 0.f);

    // ===== Phase B (4 GEMMs): powers XB^2..XB^4; Mb order 3, M3b order 4 =====
    k_build_EW<<<dim3(h / 256, h), blk, 0, stream>>>(w, dvec, Eb_, Edb, Edf, h);
    k_build_R<<<dim3(h / 32, h / 32), dim3(32, 8), 0, stream>>>(Edf, dvec, R, h, dt);
    // B1: XB = dt*(Ed @ E^T) + R -> XBf + XBb + XBT
    gemm_bf16<1, 2, 4><<<gHH, blk, 0, stream>>>(
        Edb, Eb_, XBf, nullptr, XBb, nullptr, nullptr, XBT, R, nf32, nu16,
        h, h, h, dt, 1.f, 0.f, 0.f, 0.f, 0.f, 0.f, 0.f, 0.f, 0.f);
    // B2: P2 = XB^2 -> P2f + P2b
    gemm_bf16<1, 2, 4><<<gHH, blk, 0, stream>>>(
        XBb, XBT, P2f, nullptr, P2b, nullptr, nullptr, nullptr, nf32, nf32, nu16,
        h, h, h, 1.f, 0.f, 0.f, 0.f, 0.f, 0.f, 0.f, 0.f, 0.f, 0.f);
    // B3: acc = P2@XB = XB^3 ;  Mb = acc/6 + XB + XB^2/2 -> MbT (CbT)
    //     v2 = acc = XB^3 -> P3f (C2) + P3b (Cb2)
    gemm_bf16<1, 2, 4><<<gHH, blk, 0, stream>>>(
        P2b, XBT, nullptr, P3f, nullptr, P3b, nullptr, MbT, XBf, P2f, nu16,
        h, h, h, 1.f / 6.f, 1.f, 0.5f, 0.f, 1.f, 0.f, 0.f, 0.f, 0.f, 0.f);
    // B4: acc = P3@XB = XB^4 ; M3bT = 3.375 acc + 4.5 XB^3 + 4.5 XB^2 + 3 XB
    gemm_bf16<1, 2, 4><<<gHH, blk, 0, stream>>>(
        P3b, XBT, nullptr, nullptr, nullptr, nullptr, nullptr, M3bTb,
        P3f, P2f, XBb,
        h, h, h, 3.375f, 4.5f, 4.5f, 3.f, 0.f, 0.f, 0.f, 0.f, 0.f, 0.f);

    // ===== Phase C: forcing chain F -> F2 -> F3 =====
    k_tsplit<<<dim3(h / 32, n / 32), dim3(32, 8), 0, stream>>>(x0, x0T, n, h);
    // F = dt*(Pm@x0) + dt*x0 -> Ff (f32) + FTb (bf16 T)
    gemm_bf16<2, 2, 4><<<gHN, blk, 0, stream>>>(
        Pmb, x0T, Ff, nullptr, nullptr, nullptr, nullptr, FTb, x0, nf32, nu16,
        n, h, n, dt, dt, 0.f, 0.f, 0.f, 0.f, 0.f, 0.f, 0.f, 0.f);
    // u = Ma@F + F -> uf + ub
    gemm_bf16<2, 2, 4><<<gHN, blk, 0, stream>>>(
        Mah, FTb, uf, nullptr, ub, nullptr, nullptr, nullptr, Ff, nf32, nu16,
        n, h, n, 1.f, 1.f, 0.f, 0.f, 0.f, 0.f, 0.f, 0.f, 0.f, 0.f);
    // F2 = u@Mb + u + F -> F2f + F2Tb
    gemm_bf16<2, 2, 4><<<gHN, blk, 0, stream>>>(
        ub, MbT, F2f, nullptr, nullptr, nullptr, nullptr, F2Tb, uf, Ff, nu16,
        n, h, h, 1.f, 1.f, 1.f, 0.f, 0.f, 0.f, 0.f, 0.f, 0.f, 0.f);
    // v = Ma@F2 + F2 -> vf + vb
    gemm_bf16<2, 2, 4><<<gHN, blk, 0, stream>>>(
        Mah, F2Tb, vf, nullptr, vb, nullptr, nullptr, nullptr, F2f, nf32, nu16,
        n, h, n, 1.f, 1.f, 0.f, 0.f, 0.f, 0.f, 0.f, 0.f, 0.f, 0.f);
    // F3 = v@Mb + v + F -> F3f
    gemm_bf16<2, 2, 4><<<gHN, blk, 0, stream>>>(
        vb, MbT, F3f, nullptr, nullptr, nullptr, nullptr, nullptr, vf, Ff, nu16,
        n, h, h, 1.f, 1.f, 1.f, 0.f, 0.f, 0.f, 0.f, 0.f, 0.f, 0.f);

    // ===== scan: 3 triple-steps (total 9 = int(1.0 // 0.1)) =====
    k_tsplit<<<dim3(h / 32, n / 32), dim3(32, 8), 0, stream>>>(x, zt, n, h);
    const float* zf = x;
    for (int s = 0; s < 3; ++s) {
        // G1: tf = M3a@z + z ; tb16 = bf16(tf)
        gemm_bf16<2, 2, 4><<<gHN, blk, 0, stream>>>(
            M3ah, zt, tf, nullptr, tb16, nullptr, nullptr, nullptr, zf, nf32, nu16,
            n, h, n, 1.f, 1.f, 0.f, 0.f, 0.f, 0.f, 0.f, 0.f, 0.f, 0.f);
        // G2: z''' = t@M3b + t + F3 -> za (f32) + zt (bf16 T) [last: d_out]
        float* zout = (s == 2) ? (float*)d_out : za;
        gemm_bf16<2, 2, 4><<<gHN, blk, 0, stream>>>(
            tb16, M3bTb, zout, nullptr, nullptr, nullptr, nullptr,
            (s == 2) ? nullptr : zt, tf, F3f, nu16,
            n, h, h, 1.f, 1.f, 1.f, 0.f, 0.f, 0.f, 0.f, 0.f, 0.f, 0.f);
        zf = za;
    }
}

// Round 12
// 353.037 us; speedup vs baseline: 1.5661x; 1.0717x over previous
//
#include <hip/hip_runtime.h>

typedef __attribute__((ext_vector_type(8))) short short8v;
typedef __attribute__((ext_vector_type(4))) float f32x4;

typedef const __attribute__((address_space(1))) void gvoid_t;
typedef __attribute__((address_space(3))) void svoid_t;

__device__ __forceinline__ unsigned short f2b(float f) {
    unsigned u = __float_as_uint(f);
    unsigned r = (u + 0x7fffu + ((u >> 16) & 1u)) >> 16;
    return (unsigned short)r;
}
__device__ __forceinline__ float b2f(unsigned short h) {
    return __uint_as_float((unsigned)h << 16);
}

// ---------------- elementwise / setup kernels ----------------

__global__ void k_build_A(const float* __restrict__ adj,
                          const float* __restrict__ alpha,
                          float* __restrict__ Xs, unsigned short* __restrict__ Xb,
                          int n, float scale)
{
    int j = blockIdx.x * 256 + threadIdx.x;
    int i = blockIdx.y;
    if (j >= n) return;
    size_t idx = (size_t)i * n + j;
    float s = 1.f / (1.f + expf(-alpha[i]));
    float v = scale * s * (adj[idx] - (i == j ? 1.f : 0.f));
    Xs[idx] = v;
    Xb[idx] = f2b(v);
}

__global__ void k_build_EW(const float* __restrict__ w,
                           const float* __restrict__ d,
                           unsigned short* __restrict__ Eb,
                           unsigned short* __restrict__ Edb,
                           float* __restrict__ Edf, int h)
{
    int j = blockIdx.x * 256 + threadIdx.x;
    int i = blockIdx.y;
    if (j >= h) return;
    size_t idx = (size_t)i * h + j;
    float e = w[idx] - (i == j ? 1.f : 0.f);
    float dc = fminf(fmaxf(d[j], 0.f), 1.f);
    Eb[idx] = f2b(e);
    float ed = e * dc;
    Edb[idx] = f2b(ed);
    Edf[idx] = ed;
}

__global__ void k_build_R(const float* __restrict__ Ed,
                          const float* __restrict__ d,
                          float* __restrict__ R, int h, float dt)
{
    __shared__ float tile[32][33];
    int bx = blockIdx.x * 32, by = blockIdx.y * 32;
    int tx = threadIdx.x, ty = threadIdx.y;
    #pragma unroll
    for (int r = 0; r < 32; r += 8)
        tile[ty + r][tx] = Ed[(size_t)(bx + ty + r) * h + by + tx];
    __syncthreads();
    #pragma unroll
    for (int r = 0; r < 32; r += 8) {
        int i = by + ty + r, j = bx + tx;
        float v = Ed[(size_t)i * h + j] + tile[tx][ty + r];
        if (i == j) v += fminf(fmaxf(d[i], 0.f), 1.f) - 1.f;
        R[(size_t)i * h + j] = dt * v;
    }
}

__global__ void k_tsplit(const float* __restrict__ in,
                         unsigned short* __restrict__ outT, int R, int C)
{
    __shared__ float tile[32][33];
    int bx = blockIdx.x * 32, by = blockIdx.y * 32;
    int tx = threadIdx.x, ty = threadIdx.y;
    #pragma unroll
    for (int r = 0; r < 32; r += 8)
        tile[ty + r][tx] = in[(size_t)(by + ty + r) * C + bx + tx];
    __syncthreads();
    #pragma unroll
    for (int r = 0; r < 32; r += 8)
        outT[(size_t)(bx + ty + r) * R + by + tx] = f2b(tile[tx][ty + r]);
}

// ------- bf16 MFMA GEMM: BM=FM*32 x BN=FN*32 tile, BK=64, 2-buffer ----------
// counted-vmcnt pipeline (R8/R10-proven). R12: 64x32 tiles (FM=2,FN=1) on all
// n-row GEMMs -> 1024-2048 blocks, 4-6 blocks/CU (TLP >> per-wave AI in this
// latency-bound regime, per R8/R9/R10 A/B evidence). LDS 24KB (2 buffers).
// acc = A @ B  (A: MxK bf16 row-major; BT: NxK bf16 row-major = B transposed)
// v  = alpha*acc + beta*D + g2*D2 + g3*b2f(Db) -> C (f32), Cb (bf16), CbT ([N][M] bf16)
// v2 = pa*acc + pb*D + pc*b2f(Db)              -> C2 (f32), Cb2 (bf16)
// v3 = qa*acc + qb*D + qc*b2f(Db)              -> Cb3 (bf16)
// 256 threads = 4 waves (2x2), per-wave (FM*16)x(FN*16).
// LDS: linear global_load_lds dest; XOR-swizzled source + swizzled ds_read
// (rule #21 both-sides) -> 0 bank conflicts (R5-R11 verified).
// XCD row-stripe swizzle: XCD q owns gridDim.y/8 row-blocks x all cols
// (A-panel L2-resident per XCD). Requires gridDim.y % 8 == 0.

template<int FM, int FN, int MW>
__global__ __launch_bounds__(256, MW)
void gemm_bf16(const unsigned short* __restrict__ A,
               const unsigned short* __restrict__ BT,
               float* __restrict__ C,
               float* __restrict__ C2,
               unsigned short* __restrict__ Cb,
               unsigned short* __restrict__ Cb2,
               unsigned short* __restrict__ Cb3,
               unsigned short* __restrict__ CbT,
               const float* __restrict__ D,
               const float* __restrict__ D2,
               const unsigned short* __restrict__ Db,
               int M, int N, int K,
               float alpha, float beta, float g2, float g3,
               float pa, float pb, float pc,
               float qa, float qb, float qc)
{
    constexpr int BM = FM * 32, BN = FN * 32, BK = 64;
    constexpr int AIT = BM * BK / (8 * 256);   // 16B chunks per thread (A)
    constexpr int BIT = BN * BK / (8 * 256);
    constexpr int LPT = AIT + BIT;
    __shared__ unsigned short As[2][BM * BK];
    __shared__ unsigned short Bs[2][BN * BK];

    // XCD row-stripe swizzle (requires gridDim.y % 8 == 0)
    int bid = blockIdx.y * gridDim.x + blockIdx.x;
    int rpx = gridDim.y >> 3;
    int q = bid & 7, c = bid >> 3;
    int by = q * rpx + (c % rpx);
    int bx = c / rpx;

    const int tid  = threadIdx.x;
    const int lane = tid & 63;
    const int wave = tid >> 6;
    const int wr = wave >> 1, wc = wave & 1;   // 2 x 2 wave grid
    const int l16 = lane & 15, l4 = lane >> 4;
    const int brow = by * BM, bcol = bx * BN;

    f32x4 acc[FM][FN];
    #pragma unroll
    for (int m = 0; m < FM; ++m)
        #pragma unroll
        for (int j = 0; j < FN; ++j)
            acc[m][j] = (f32x4){0.f, 0.f, 0.f, 0.f};

    const unsigned short* Ab = A + (size_t)brow * K;
    const unsigned short* Bb = BT + (size_t)bcol * K;
    const int nt = K / BK;

    auto stage = [&](int b, int k0) {
        #pragma unroll
        for (int it = 0; it < AIT; ++it) {
            int cb = it * 256 + wave * 64;          // wave-uniform chunk base
            int ch = cb + lane;
            int r = ch >> 3, cc = ch & 7;
            int cs = cc ^ (r & 7);                  // inverse-swizzled source
            __builtin_amdgcn_global_load_lds(
                (gvoid_t*)(Ab + (size_t)r * K + k0 + cs * 8),
                (svoid_t*)(&As[b][cb * 8]), 16, 0, 0);
        }
        #pragma unroll
        for (int it = 0; it < BIT; ++it) {
            int cb = it * 256 + wave * 64;
            int ch = cb + lane;
            int r = ch >> 3, cc = ch & 7;
            int cs = cc ^ (r & 7);
            __builtin_amdgcn_global_load_lds(
                (gvoid_t*)(Bb + (size_t)r * K + k0 + cs * 8),
                (svoid_t*)(&Bs[b][cb * 8]), 16, 0, 0);
        }
    };

    stage(0, 0);
    stage(1, BK);

    for (int t = 0; t < nt; ++t) {
        const int cur = t & 1;
        if (t + 1 < nt) {
            asm volatile("s_waitcnt vmcnt(%0)" :: "i"(LPT) : "memory");
        } else {
            asm volatile("s_waitcnt vmcnt(0)" ::: "memory");
        }
        __builtin_amdgcn_s_barrier();
        asm volatile("" ::: "memory");
        __builtin_amdgcn_sched_barrier(0);

        short8v af[FM][2], bf[FN][2];
        #pragma unroll
        for (int m = 0; m < FM; ++m) {
            int r = wr * FM * 16 + m * 16 + l16;
            #pragma unroll
            for (int hf = 0; hf < 2; ++hf) {
                int cs = (hf * 4 + l4) ^ (r & 7);    // swizzled read
                af[m][hf] = *(const short8v*)&As[cur][r * BK + cs * 8];
            }
        }
        #pragma unroll
        for (int j = 0; j < FN; ++j) {
            int r = wc * FN * 16 + j * 16 + l16;
            #pragma unroll
            for (int hf = 0; hf < 2; ++hf) {
                int cs = (hf * 4 + l4) ^ (r & 7);
                bf[j][hf] = *(const short8v*)&Bs[cur][r * BK + cs * 8];
            }
        }
        __builtin_amdgcn_s_setprio(1);
        #pragma unroll
        for (int hf = 0; hf < 2; ++hf)
            #pragma unroll
            for (int m = 0; m < FM; ++m)
                #pragma unroll
                for (int j = 0; j < FN; ++j)
                    acc[m][j] = __builtin_amdgcn_mfma_f32_16x16x32_bf16(
                        af[m][hf], bf[j][hf], acc[m][j], 0, 0, 0);
        __builtin_amdgcn_s_setprio(0);
        __builtin_amdgcn_sched_barrier(0);
        __builtin_amdgcn_s_barrier();
        asm volatile("" ::: "memory");
        if (t + 2 < nt) stage(cur, (t + 2) * BK);   // reuse just-freed buffer
    }

    #pragma unroll
    for (int m = 0; m < FM; ++m) {
        #pragma unroll
        for (int j = 0; j < FN; ++j) {
            const int row0 = brow + wr * FM * 16 + m * 16 + l4 * 4;
            const int col  = bcol + wc * FN * 16 + j * 16 + l16;
            float vv[4];
            #pragma unroll
            for (int q2 = 0; q2 < 4; ++q2) {
                size_t idx = (size_t)(row0 + q2) * N + col;
                float a0 = acc[m][j][q2];
                float v = alpha * a0;
                float dv = 0.f, dbv = 0.f;
                if (D)  { dv = D[idx]; v = fmaf(beta, dv, v); }
                if (D2) v = fmaf(g2, D2[idx], v);
                if (Db) { dbv = b2f(Db[idx]); v = fmaf(g3, dbv, v); }
                vv[q2] = v;
                if (C)  C[idx] = v;
                if (Cb) Cb[idx] = f2b(v);
                if (C2 || Cb2) {
                    float v2 = pa * a0;
                    if (D)  v2 = fmaf(pb, dv, v2);
                    if (Db) v2 = fmaf(pc, dbv, v2);
                    if (C2)  C2[idx] = v2;
                    if (Cb2) Cb2[idx] = f2b(v2);
                }
                if (Cb3) {
                    float v3 = qa * a0;
                    if (D)  v3 = fmaf(qb, dv, v3);
                    if (Db) v3 = fmaf(qc, dbv, v3);
                    Cb3[idx] = f2b(v3);
                }
            }
            if (CbT) {
                ushort4 t4;
                t4.x = f2b(vv[0]); t4.y = f2b(vv[1]);
                t4.z = f2b(vv[2]); t4.w = f2b(vv[3]);
                *reinterpret_cast<ushort4*>(&CbT[(size_t)col * M + row0]) = t4;
            }
        }
    }
}

// ---------------- host orchestration ----------------

extern "C" void kernel_launch(void* const* d_in, const int* in_sizes, int n_in,
                              void* d_out, int out_size, void* d_ws, size_t ws_size,
                              hipStream_t stream)
{
    const float* x     = (const float*)d_in[0];   // [n, h]
    const float* x0    = (const float*)d_in[1];   // [n, h]
    const float* adj   = (const float*)d_in[2];   // [n, n]
    const float* alpha = (const float*)d_in[3];   // [n]
    const float* w     = (const float*)d_in[4];   // [h, h]
    const float* dvec  = (const float*)d_in[5];   // [h]

    const int n = in_sizes[3];      // 2048
    const int h = in_sizes[5];      // 1024
    const size_t MB = 1u << 20;
    char* ws = (char*)d_ws;

    typedef unsigned short u16;
    // ---- workspace (MiB offsets, phase-overlaid; peak 72 MiB) ----
    // Phase A
    float* Xs    = (float*)(ws + 0 * MB);    // 16, dies after A1
    u16*   XAb   = (u16*)(ws + 16 * MB);     // 8,  dies after A1
    u16*   XAT   = (u16*)(ws + 24 * MB);     // 8,  dies after A1
    u16*   Mah   = (u16*)(ws + 32 * MB);     // 8,  dies after v-GEMM
    u16*   Pmb   = (u16*)(ws + 40 * MB);     // 8,  dies after F-GEMM
    u16*   M3ah  = (u16*)(ws + 48 * MB);     // 8,  persists (scan)
    u16*   MbT   = (u16*)(ws + 56 * MB);     // 2,  dies after F3
    u16*   M3bTb = (u16*)(ws + 58 * MB);     // 2,  persists (scan)
    // Phase B (over [0,32); phase-A temps dead)
    u16*   Eb_   = (u16*)(ws + 0 * MB);      // 2
    u16*   Edb   = (u16*)(ws + 2 * MB);      // 2
    float* Edf   = (float*)(ws + 4 * MB);    // 4
    float* R     = (float*)(ws + 8 * MB);    // 4
    float* XBf   = (float*)(ws + 12 * MB);   // 4
    u16*   XBb   = (u16*)(ws + 16 * MB);     // 2
    u16*   XBT   = (u16*)(ws + 18 * MB);     // 2
    float* P2f   = (float*)(ws + 20 * MB);   // 4
    u16*   P2b   = (u16*)(ws + 24 * MB);     // 2
    float* P3f   = (float*)(ws + 26 * MB);   // 4
    u16*   P3b   = (u16*)(ws + 30 * MB);     // 2
    // Phase C (over [0,32) after B; + high slots)
    u16*   x0T   = (u16*)(ws + 0 * MB);      // 4, dies after F
    float* Ff    = (float*)(ws + 4 * MB);    // 8, dies after F3
    u16*   FTb   = (u16*)(ws + 12 * MB);     // 4, dies after u
    float* uf    = (float*)(ws + 16 * MB);   // 8, dies after F2
    u16*   ub    = (u16*)(ws + 24 * MB);     // 4, dies after F2
    float* F2f   = (float*)(ws + 60 * MB);   // 8, dies after v
    u16*   F2Tb  = (u16*)(ws + 12 * MB);     // 4 (over FTb), dies after v
    float* vf    = (float*)(ws + 16 * MB);   // 8 (over uf), dies after F3
    u16*   vb    = (u16*)(ws + 24 * MB);     // 4 (over ub), dies after F3
    float* F3f   = (float*)(ws + 40 * MB);   // 8 (over Pmb, dead), persists
    u16*   zt    = (u16*)(ws + 68 * MB);     // 4, scan state
    float* tf    = (float*)(ws + 0 * MB);    // 8 (scan)
    u16*   tb16  = (u16*)(ws + 8 * MB);      // 4 (scan)
    float* za    = (float*)(ws + 16 * MB);   // 8 (scan, over vf dead)

    const dim3 blk(256);
    const dim3 gNN(n / 32, n / 64);    // 64x32 = 2048 blocks (6/CU), 64x32 tile
    const dim3 gHN(h / 32, n / 64);    // 32x32 = 1024 blocks (4/CU), 64x32 tile
    const dim3 gHH(h / 64, h / 32);    // 16x32 = 512 blocks  (2/CU), 32x64 tile
    const float dt = 0.1f;
    const u16* nu16 = nullptr;
    const float* nf32 = nullptr;

    // ===== Phase A: single n^3 GEMM. acc = X^2; epilogue emits all three =====
    //   Ma  =  X  + X^2/2   -> Mah  (Cb:  alpha=1/2, D=Xs beta=1)
    //   Pm  =  X/2 + X^2/6  -> Pmb  (Cb2: pa=1/6,  pb=1/2)
    //   M3a = 3X + 4.5 X^2  -> M3ah (Cb3: qa=4.5,  qb=3)
    k_build_A<<<dim3(n / 256, n), blk, 0, stream>>>(adj, alpha, Xs, XAb, n, 0.5f * dt);
    k_tsplit<<<dim3(n / 32, n / 32), dim3(32, 8), 0, stream>>>(Xs, XAT, n, n);
    gemm_bf16<2, 1, 4><<<gNN, blk, 0, stream>>>(
        XAb, XAT, nullptr, nullptr, Mah, Pmb, M3ah, nullptr, Xs, nf32, nu16,
        n, n, n, 0.5f, 1.f, 0.f, 0.f,
        1.f / 6.f, 0.5f, 0.f, 4.5f, 3.f, 0.f);

    // ===== Phase B (4 GEMMs): powers XB^2..XB^4; Mb order 3, M3b order 4 =====
    k_build_EW<<<dim3(h / 256, h), blk, 0, stream>>>(w, dvec, Eb_, Edb, Edf, h);
    k_build_R<<<dim3(h / 32, h / 32), dim3(32, 8), 0, stream>>>(Edf, dvec, R, h, dt);
    // B1: XB = dt*(Ed @ E^T) + R -> XBf + XBb + XBT
    gemm_bf16<1, 2, 4><<<gHH, blk, 0, stream>>>(
        Edb, Eb_, XBf, nullptr, XBb, nullptr, nullptr, XBT, R, nf32, nu16,
        h, h, h, dt, 1.f, 0.f, 0.f, 0.f, 0.f, 0.f, 0.f, 0.f, 0.f);
    // B2: P2 = XB^2 -> P2f + P2b
    gemm_bf16<1, 2, 4><<<gHH, blk, 0, stream>>>(
        XBb, XBT, P2f, nullptr, P2b, nullptr, nullptr, nullptr, nf32, nf32, nu16,
        h, h, h, 1.f, 0.f, 0.f, 0.f, 0.f, 0.f, 0.f, 0.f, 0.f, 0.f);
    // B3: acc = P2@XB = XB^3 ;  Mb = acc/6 + XB + XB^2/2 -> MbT (CbT)
    //     v2 = acc = XB^3 -> P3f (C2) + P3b (Cb2)
    gemm_bf16<1, 2, 4><<<gHH, blk, 0, stream>>>(
        P2b, XBT, nullptr, P3f, nullptr, P3b, nullptr, MbT, XBf, P2f, nu16,
        h, h, h, 1.f / 6.f, 1.f, 0.5f, 0.f, 1.f, 0.f, 0.f, 0.f, 0.f, 0.f);
    // B4: acc = P3@XB = XB^4 ; M3bT = 3.375 acc + 4.5 XB^3 + 4.5 XB^2 + 3 XB
    gemm_bf16<1, 2, 4><<<gHH, blk, 0, stream>>>(
        P3b, XBT, nullptr, nullptr, nullptr, nullptr, nullptr, M3bTb,
        P3f, P2f, XBb,
        h, h, h, 3.375f, 4.5f, 4.5f, 3.f, 0.f, 0.f, 0.f, 0.f, 0.f, 0.f);

    // ===== Phase C: forcing chain F -> F2 -> F3 =====
    k_tsplit<<<dim3(h / 32, n / 32), dim3(32, 8), 0, stream>>>(x0, x0T, n, h);
    // F = dt*(Pm@x0) + dt*x0 -> Ff (f32) + FTb (bf16 T)
    gemm_bf16<2, 1, 4><<<gHN, blk, 0, stream>>>(
        Pmb, x0T, Ff, nullptr, nullptr, nullptr, nullptr, FTb, x0, nf32, nu16,
        n, h, n, dt, dt, 0.f, 0.f, 0.f, 0.f, 0.f, 0.f, 0.f, 0.f);
    // u = Ma@F + F -> uf + ub
    gemm_bf16<2, 1, 4><<<gHN, blk, 0, stream>>>(
        Mah, FTb, uf, nullptr, ub, nullptr, nullptr, nullptr, Ff, nf32, nu16,
        n, h, n, 1.f, 1.f, 0.f, 0.f, 0.f, 0.f, 0.f, 0.f, 0.f, 0.f);
    // F2 = u@Mb + u + F -> F2f + F2Tb
    gemm_bf16<2, 1, 4><<<gHN, blk, 0, stream>>>(
        ub, MbT, F2f, nullptr, nullptr, nullptr, nullptr, F2Tb, uf, Ff, nu16,
        n, h, h, 1.f, 1.f, 1.f, 0.f, 0.f, 0.f, 0.f, 0.f, 0.f, 0.f);
    // v = Ma@F2 + F2 -> vf + vb
    gemm_bf16<2, 1, 4><<<gHN, blk, 0, stream>>>(
        Mah, F2Tb, vf, nullptr, vb, nullptr, nullptr, nullptr, F2f, nf32, nu16,
        n, h, n, 1.f, 1.f, 0.f, 0.f, 0.f, 0.f, 0.f, 0.f, 0.f, 0.f);
    // F3 = v@Mb + v + F -> F3f
    gemm_bf16<2, 1, 4><<<gHN, blk, 0, stream>>>(
        vb, MbT, F3f, nullptr, nullptr, nullptr, nullptr, nullptr, vf, Ff, nu16,
        n, h, h, 1.f, 1.f, 1.f, 0.f, 0.f, 0.f, 0.f, 0.f, 0.f, 0.f);

    // ===== scan: 3 triple-steps (total 9 = int(1.0 // 0.1)) =====
    k_tsplit<<<dim3(h / 32, n / 32), dim3(32, 8), 0, stream>>>(x, zt, n, h);
    const float* zf = x;
    for (int s = 0; s < 3; ++s) {
        // G1: tf = M3a@z + z ; tb16 = bf16(tf)
        gemm_bf16<2, 1, 4><<<gHN, blk, 0, stream>>>(
            M3ah, zt, tf, nullptr, tb16, nullptr, nullptr, nullptr, zf, nf32, nu16,
            n, h, n, 1.f, 1.f, 0.f, 0.f, 0.f, 0.f, 0.f, 0.f, 0.f, 0.f);
        // G2: z''' = t@M3b + t + F3 -> za (f32) + zt (bf16 T) [last: d_out]
        float* zout = (s == 2) ? (float*)d_out : za;
        gemm_bf16<2, 1, 4><<<gHN, blk, 0, stream>>>(
            tb16, M3bTb, zout, nullptr, nullptr, nullptr, nullptr,
            (s == 2) ? nullptr : zt, tf, F3f, nu16,
            n, h, h, 1.f, 1.f, 1.f, 0.f, 0.f, 0.f, 0.f, 0.f, 0.f, 0.f);
        zf = za;
    }
}

// Round 13
// 323.199 us; speedup vs baseline: 1.7106x; 1.0923x over previous
//
#include <hip/hip_runtime.h>

typedef __attribute__((ext_vector_type(8))) short short8v;
typedef __attribute__((ext_vector_type(4))) float f32x4;

typedef const __attribute__((address_space(1))) void gvoid_t;
typedef __attribute__((address_space(3))) void svoid_t;

__device__ __forceinline__ unsigned short f2b(float f) {
    unsigned u = __float_as_uint(f);
    unsigned r = (u + 0x7fffu + ((u >> 16) & 1u)) >> 16;
    return (unsigned short)r;
}
__device__ __forceinline__ float b2f(unsigned short h) {
    return __uint_as_float((unsigned)h << 16);
}

// ---------------- elementwise / setup kernels ----------------

// Fused: X = dt*A = scale*sigmoid(alpha_i)*(adj - I) -> XAb (bf16 row-major)
// + XATb (bf16 transposed). No f32 X materialization (outputs are bf16-
// quantized downstream anyway; <=1 ulp difference).
__global__ void k_build_AT(const float* __restrict__ adj,
                           const float* __restrict__ alpha,
                           unsigned short* __restrict__ XAb,
                           unsigned short* __restrict__ XATb,
                           int n, float scale)
{
    __shared__ float tile[32][33];
    int bx = blockIdx.x * 32, by = blockIdx.y * 32;
    int tx = threadIdx.x, ty = threadIdx.y;
    #pragma unroll
    for (int r = 0; r < 32; r += 8) {
        int i = by + ty + r, j = bx + tx;
        float s = 1.f / (1.f + expf(-alpha[i]));
        float v = scale * s * (adj[(size_t)i * n + j] - (i == j ? 1.f : 0.f));
        XAb[(size_t)i * n + j] = f2b(v);
        tile[ty + r][tx] = v;
    }
    __syncthreads();
    #pragma unroll
    for (int r = 0; r < 32; r += 8)
        XATb[(size_t)(bx + ty + r) * n + by + tx] = f2b(tile[tx][ty + r]);
}

__global__ void k_build_EW(const float* __restrict__ w,
                           const float* __restrict__ d,
                           unsigned short* __restrict__ Eb,
                           unsigned short* __restrict__ Edb,
                           float* __restrict__ Edf, int h)
{
    int j = blockIdx.x * 256 + threadIdx.x;
    int i = blockIdx.y;
    if (j >= h) return;
    size_t idx = (size_t)i * h + j;
    float e = w[idx] - (i == j ? 1.f : 0.f);
    float dc = fminf(fmaxf(d[j], 0.f), 1.f);
    Eb[idx] = f2b(e);
    float ed = e * dc;
    Edb[idx] = f2b(ed);
    Edf[idx] = ed;
}

__global__ void k_build_R(const float* __restrict__ Ed,
                          const float* __restrict__ d,
                          float* __restrict__ R, int h, float dt)
{
    __shared__ float tile[32][33];
    int bx = blockIdx.x * 32, by = blockIdx.y * 32;
    int tx = threadIdx.x, ty = threadIdx.y;
    #pragma unroll
    for (int r = 0; r < 32; r += 8)
        tile[ty + r][tx] = Ed[(size_t)(bx + ty + r) * h + by + tx];
    __syncthreads();
    #pragma unroll
    for (int r = 0; r < 32; r += 8) {
        int i = by + ty + r, j = bx + tx;
        float v = Ed[(size_t)i * h + j] + tile[tx][ty + r];
        if (i == j) v += fminf(fmaxf(d[i], 0.f), 1.f) - 1.f;
        R[(size_t)i * h + j] = dt * v;
    }
}

// two transposes in one dispatch: in0,in1 [R][C] f32 -> out0,out1 [C][R] bf16
__global__ void k_tsplit2(const float* __restrict__ in0,
                          const float* __restrict__ in1,
                          unsigned short* __restrict__ out0,
                          unsigned short* __restrict__ out1, int R, int C)
{
    __shared__ float tile[32][33];
    int bx = blockIdx.x * 32, by = blockIdx.y * 32;
    int tx = threadIdx.x, ty = threadIdx.y;
    #pragma unroll
    for (int r = 0; r < 32; r += 8)
        tile[ty + r][tx] = in0[(size_t)(by + ty + r) * C + bx + tx];
    __syncthreads();
    #pragma unroll
    for (int r = 0; r < 32; r += 8)
        out0[(size_t)(bx + ty + r) * R + by + tx] = f2b(tile[tx][ty + r]);
    __syncthreads();
    #pragma unroll
    for (int r = 0; r < 32; r += 8)
        tile[ty + r][tx] = in1[(size_t)(by + ty + r) * C + bx + tx];
    __syncthreads();
    #pragma unroll
    for (int r = 0; r < 32; r += 8)
        out1[(size_t)(bx + ty + r) * R + by + tx] = f2b(tile[tx][ty + r]);
}

// ------- bf16 MFMA GEMM: BM=FM*32 x BN=FN*32 tile, BK=64, 2-buffer ----------
// counted-vmcnt pipeline. Per-class tiles (R12 A/B evidence): n^3 -> 64x64
// (4/CU, best per-GEMM); n x h -> 64x32 (4-6/CU, TLP-bound regime).
// acc = A @ B  (A: MxK bf16 row-major; BT: NxK bf16 row-major = B transposed)
// v  = alpha*acc + beta*D + g2*D2 + g3*b2f(Db) -> C (f32), Cb (bf16), CbT ([N][M] bf16)
// v2 = pa*acc + pb*D + pc*b2f(Db)              -> C2 (f32), Cb2 (bf16)
// v3 = qa*acc + qb*D + qc*b2f(Db)              -> Cb3 (bf16)
// 256 threads = 4 waves (2x2), per-wave (FM*16)x(FN*16).
// LDS: linear global_load_lds dest; XOR-swizzled source + swizzled ds_read
// (rule #21 both-sides) -> 0 bank conflicts (R5-R12 verified).
// XCD row-stripe swizzle: XCD q owns gridDim.y/8 row-blocks x all cols.

template<int FM, int FN, int MW>
__global__ __launch_bounds__(256, MW)
void gemm_bf16(const unsigned short* __restrict__ A,
               const unsigned short* __restrict__ BT,
               float* __restrict__ C,
               float* __restrict__ C2,
               unsigned short* __restrict__ Cb,
               unsigned short* __restrict__ Cb2,
               unsigned short* __restrict__ Cb3,
               unsigned short* __restrict__ CbT,
               const float* __restrict__ D,
               const float* __restrict__ D2,
               const unsigned short* __restrict__ Db,
               int M, int N, int K,
               float alpha, float beta, float g2, float g3,
               float pa, float pb, float pc,
               float qa, float qb, float qc)
{
    constexpr int BM = FM * 32, BN = FN * 32, BK = 64;
    constexpr int AIT = BM * BK / (8 * 256);   // 16B chunks per thread (A)
    constexpr int BIT = BN * BK / (8 * 256);
    constexpr int LPT = AIT + BIT;
    __shared__ unsigned short As[2][BM * BK];
    __shared__ unsigned short Bs[2][BN * BK];

    // XCD row-stripe swizzle (requires gridDim.y % 8 == 0)
    int bid = blockIdx.y * gridDim.x + blockIdx.x;
    int rpx = gridDim.y >> 3;
    int q = bid & 7, c = bid >> 3;
    int by = q * rpx + (c % rpx);
    int bx = c / rpx;

    const int tid  = threadIdx.x;
    const int lane = tid & 63;
    const int wave = tid >> 6;
    const int wr = wave >> 1, wc = wave & 1;   // 2 x 2 wave grid
    const int l16 = lane & 15, l4 = lane >> 4;
    const int brow = by * BM, bcol = bx * BN;

    f32x4 acc[FM][FN];
    #pragma unroll
    for (int m = 0; m < FM; ++m)
        #pragma unroll
        for (int j = 0; j < FN; ++j)
            acc[m][j] = (f32x4){0.f, 0.f, 0.f, 0.f};

    const unsigned short* Ab = A + (size_t)brow * K;
    const unsigned short* Bb = BT + (size_t)bcol * K;
    const int nt = K / BK;

    auto stage = [&](int b, int k0) {
        #pragma unroll
        for (int it = 0; it < AIT; ++it) {
            int cb = it * 256 + wave * 64;          // wave-uniform chunk base
            int ch = cb + lane;
            int r = ch >> 3, cc = ch & 7;
            int cs = cc ^ (r & 7);                  // inverse-swizzled source
            __builtin_amdgcn_global_load_lds(
                (gvoid_t*)(Ab + (size_t)r * K + k0 + cs * 8),
                (svoid_t*)(&As[b][cb * 8]), 16, 0, 0);
        }
        #pragma unroll
        for (int it = 0; it < BIT; ++it) {
            int cb = it * 256 + wave * 64;
            int ch = cb + lane;
            int r = ch >> 3, cc = ch & 7;
            int cs = cc ^ (r & 7);
            __builtin_amdgcn_global_load_lds(
                (gvoid_t*)(Bb + (size_t)r * K + k0 + cs * 8),
                (svoid_t*)(&Bs[b][cb * 8]), 16, 0, 0);
        }
    };

    stage(0, 0);
    stage(1, BK);

    for (int t = 0; t < nt; ++t) {
        const int cur = t & 1;
        if (t + 1 < nt) {
            asm volatile("s_waitcnt vmcnt(%0)" :: "i"(LPT) : "memory");
        } else {
            asm volatile("s_waitcnt vmcnt(0)" ::: "memory");
        }
        __builtin_amdgcn_s_barrier();
        asm volatile("" ::: "memory");
        __builtin_amdgcn_sched_barrier(0);

        short8v af[FM][2], bf[FN][2];
        #pragma unroll
        for (int m = 0; m < FM; ++m) {
            int r = wr * FM * 16 + m * 16 + l16;
            #pragma unroll
            for (int hf = 0; hf < 2; ++hf) {
                int cs = (hf * 4 + l4) ^ (r & 7);    // swizzled read
                af[m][hf] = *(const short8v*)&As[cur][r * BK + cs * 8];
            }
        }
        #pragma unroll
        for (int j = 0; j < FN; ++j) {
            int r = wc * FN * 16 + j * 16 + l16;
            #pragma unroll
            for (int hf = 0; hf < 2; ++hf) {
                int cs = (hf * 4 + l4) ^ (r & 7);
                bf[j][hf] = *(const short8v*)&Bs[cur][r * BK + cs * 8];
            }
        }
        __builtin_amdgcn_s_setprio(1);
        #pragma unroll
        for (int hf = 0; hf < 2; ++hf)
            #pragma unroll
            for (int m = 0; m < FM; ++m)
                #pragma unroll
                for (int j = 0; j < FN; ++j)
                    acc[m][j] = __builtin_amdgcn_mfma_f32_16x16x32_bf16(
                        af[m][hf], bf[j][hf], acc[m][j], 0, 0, 0);
        __builtin_amdgcn_s_setprio(0);
        __builtin_amdgcn_sched_barrier(0);
        __builtin_amdgcn_s_barrier();
        asm volatile("" ::: "memory");
        if (t + 2 < nt) stage(cur, (t + 2) * BK);   // reuse just-freed buffer
    }

    #pragma unroll
    for (int m = 0; m < FM; ++m) {
        #pragma unroll
        for (int j = 0; j < FN; ++j) {
            const int row0 = brow + wr * FM * 16 + m * 16 + l4 * 4;
            const int col  = bcol + wc * FN * 16 + j * 16 + l16;
            float vv[4];
            #pragma unroll
            for (int q2 = 0; q2 < 4; ++q2) {
                size_t idx = (size_t)(row0 + q2) * N + col;
                float a0 = acc[m][j][q2];
                float v = alpha * a0;
                float dv = 0.f, dbv = 0.f;
                if (D)  { dv = D[idx]; v = fmaf(beta, dv, v); }
                if (D2) v = fmaf(g2, D2[idx], v);
                if (Db) { dbv = b2f(Db[idx]); v = fmaf(g3, dbv, v); }
                vv[q2] = v;
                if (C)  C[idx] = v;
                if (Cb) Cb[idx] = f2b(v);
                if (C2 || Cb2) {
                    float v2 = pa * a0;
                    if (D)  v2 = fmaf(pb, dv, v2);
                    if (Db) v2 = fmaf(pc, dbv, v2);
                    if (C2)  C2[idx] = v2;
                    if (Cb2) Cb2[idx] = f2b(v2);
                }
                if (Cb3) {
                    float v3 = qa * a0;
                    if (D)  v3 = fmaf(qb, dv, v3);
                    if (Db) v3 = fmaf(qc, dbv, v3);
                    Cb3[idx] = f2b(v3);
                }
            }
            if (CbT) {
                ushort4 t4;
                t4.x = f2b(vv[0]); t4.y = f2b(vv[1]);
                t4.z = f2b(vv[2]); t4.w = f2b(vv[3]);
                *reinterpret_cast<ushort4*>(&CbT[(size_t)col * M + row0]) = t4;
            }
        }
    }
}

// ---------------- host orchestration ----------------

extern "C" void kernel_launch(void* const* d_in, const int* in_sizes, int n_in,
                              void* d_out, int out_size, void* d_ws, size_t ws_size,
                              hipStream_t stream)
{
    const float* x     = (const float*)d_in[0];   // [n, h]
    const float* x0    = (const float*)d_in[1];   // [n, h]
    const float* adj   = (const float*)d_in[2];   // [n, n]
    const float* alpha = (const float*)d_in[3];   // [n]
    const float* w     = (const float*)d_in[4];   // [h, h]
    const float* dvec  = (const float*)d_in[5];   // [h]

    const int n = in_sizes[3];      // 2048
    const int h = in_sizes[5];      // 1024
    const size_t MB = 1u << 20;
    char* ws = (char*)d_ws;

    typedef unsigned short u16;
    // ---- workspace (MiB offsets, phase-overlaid; peak 88 MiB) ----
    u16*   XAb   = (u16*)(ws + 0 * MB);      // 8, dies after A1
    u16*   XATb  = (u16*)(ws + 8 * MB);      // 8, dies after A1
    u16*   Mah   = (u16*)(ws + 16 * MB);     // 8, dies after v-link
    u16*   Pmb   = (u16*)(ws + 24 * MB);     // 8, dies after F
    u16*   M3ah  = (u16*)(ws + 32 * MB);     // 8, persists (scan)
    u16*   MbT   = (u16*)(ws + 40 * MB);     // 2, dies after F3
    u16*   M3bTb = (u16*)(ws + 42 * MB);     // 2, persists (scan)
    // Phase B (over XAb/XATb, dead after A1)
    u16*   Eb_   = (u16*)(ws + 0 * MB);      // 2
    u16*   Edb   = (u16*)(ws + 2 * MB);      // 2
    float* Edf   = (float*)(ws + 4 * MB);    // 4
    float* R     = (float*)(ws + 8 * MB);    // 4
    float* XBf   = (float*)(ws + 12 * MB);   // 4
    u16*   XBb   = (u16*)(ws + 44 * MB);     // 2
    u16*   XBT   = (u16*)(ws + 46 * MB);     // 2
    float* P2f   = (float*)(ws + 48 * MB);   // 4
    u16*   P2b   = (u16*)(ws + 52 * MB);     // 2
    float* P3f   = (float*)(ws + 54 * MB);   // 4
    u16*   P3b   = (u16*)(ws + 58 * MB);     // 2
    // Phase C (overlays: B-phase temps dead at each write point)
    u16*   x0T   = (u16*)(ws + 0 * MB);      // 4 (over Eb_/Edb)
    float* Ff    = (float*)(ws + 4 * MB);    // 8 (over Edf/R), lives to F3
    u16*   Fb    = (u16*)(ws + 12 * MB);     // 4 (over XBf), dies after u
    u16*   FTb   = (u16*)(ws + 44 * MB);     // 4 (over XBb/XBT), dies after u
    u16*   ub    = (u16*)(ws + 48 * MB);     // 4 (over P2f), dies after F2
    u16*   F2b   = (u16*)(ws + 52 * MB);     // 4 (over P2b/P3f), dies after v
    u16*   F2Tb  = (u16*)(ws + 56 * MB);     // 4 (over P3f/P3b), dies after v
    u16*   vb    = (u16*)(ws + 60 * MB);     // 4, dies after F3
    float* F3f   = (float*)(ws + 64 * MB);   // 8, persists (scan)
    u16*   zt    = (u16*)(ws + 72 * MB);     // 4, scan state (z^T bf16)
    u16*   tb16  = (u16*)(ws + 76 * MB);     // 4, scan temp (t bf16)
    float* za    = (float*)(ws + 80 * MB);   // 8, scan state (z f32)

    const dim3 blk(256);
    const dim3 gNN(n / 64, n / 64);    // 32x32 = 1024 blocks (4/CU), 64x64 tile
    const dim3 gHN(h / 32, n / 64);    // 32x32 = 1024 blocks (4+/CU), 64x32 tile
    const dim3 gHH(h / 64, h / 32);    // 16x32 = 512 blocks, 32x64 tile
    const float dt = 0.1f;
    const u16* nu16 = nullptr;
    const float* nf32 = nullptr;

    // ===== Phase A: single n^3 GEMM. acc = X^2; epilogue emits all three =====
    //   Ma  =  X  + X^2/2   -> Mah  (Cb:  alpha=1/2, Db=XAb g3=1)
    //   Pm  =  X/2 + X^2/6  -> Pmb  (Cb2: pa=1/6,  pc=1/2)
    //   M3a = 3X + 4.5 X^2  -> M3ah (Cb3: qa=4.5,  qc=3)
    k_build_AT<<<dim3(n / 32, n / 32), dim3(32, 8), 0, stream>>>(
        adj, alpha, XAb, XATb, n, 0.5f * dt);
    gemm_bf16<2, 2, 4><<<gNN, blk, 0, stream>>>(
        XAb, XATb, nullptr, nullptr, Mah, Pmb, M3ah, nullptr, nf32, nf32, XAb,
        n, n, n, 0.5f, 0.f, 0.f, 1.f,
        1.f / 6.f, 0.f, 0.5f, 4.5f, 0.f, 3.f);

    // ===== Phase B (4 GEMMs): powers XB^2..XB^4; Mb order 3, M3b order 4 =====
    k_build_EW<<<dim3(h / 256, h), blk, 0, stream>>>(w, dvec, Eb_, Edb, Edf, h);
    k_build_R<<<dim3(h / 32, h / 32), dim3(32, 8), 0, stream>>>(Edf, dvec, R, h, dt);
    // B1: XB = dt*(Ed @ E^T) + R -> XBf + XBb + XBT
    gemm_bf16<1, 2, 4><<<gHH, blk, 0, stream>>>(
        Edb, Eb_, XBf, nullptr, XBb, nullptr, nullptr, XBT, R, nf32, nu16,
        h, h, h, dt, 1.f, 0.f, 0.f, 0.f, 0.f, 0.f, 0.f, 0.f, 0.f);
    // B2: P2 = XB^2 -> P2f + P2b
    gemm_bf16<1, 2, 4><<<gHH, blk, 0, stream>>>(
        XBb, XBT, P2f, nullptr, P2b, nullptr, nullptr, nullptr, nf32, nf32, nu16,
        h, h, h, 1.f, 0.f, 0.f, 0.f, 0.f, 0.f, 0.f, 0.f, 0.f, 0.f);
    // B3: acc = P2@XB = XB^3 ;  Mb^T = acc/6 + XB + XB^2/2 -> MbT (CbT)
    //     v2 = acc = XB^3 -> P3f (C2) + P3b (Cb2)
    gemm_bf16<1, 2, 4><<<gHH, blk, 0, stream>>>(
        P2b, XBT, nullptr, P3f, nullptr, P3b, nullptr, MbT, XBf, P2f, nu16,
        h, h, h, 1.f / 6.f, 1.f, 0.5f, 0.f, 1.f, 0.f, 0.f, 0.f, 0.f, 0.f);
    // B4: acc = P3@XB = XB^4 ; M3bT = 3.375 acc + 4.5 XB^3 + 4.5 XB^2 + 3 XB
    gemm_bf16<1, 2, 4><<<gHH, blk, 0, stream>>>(
        P3b, XBT, nullptr, nullptr, nullptr, nullptr, nullptr, M3bTb,
        P3f, P2f, XBb,
        h, h, h, 3.375f, 4.5f, 4.5f, 3.f, 0.f, 0.f, 0.f, 0.f, 0.f, 0.f);

    // ===== transposes for forcing + scan init (one dispatch) =====
    k_tsplit2<<<dim3(h / 32, n / 32), dim3(32, 8), 0, stream>>>(
        x0, x, x0T, zt, n, h);

    // ===== Phase C: forcing chain F -> F2 -> F3 (bf16 identity-carries) =====
    // F = dt*(Pm@x0) + dt*x0 -> Ff (f32) + Fb + FTb
    gemm_bf16<2, 1, 4><<<gHN, blk, 0, stream>>>(
        Pmb, x0T, Ff, nullptr, Fb, nullptr, nullptr, FTb, x0, nf32, nu16,
        n, h, n, dt, dt, 0.f, 0.f, 0.f, 0.f, 0.f, 0.f, 0.f, 0.f);
    // u = Ma@F + F -> ub
    gemm_bf16<2, 1, 4><<<gHN, blk, 0, stream>>>(
        Mah, FTb, nullptr, nullptr, ub, nullptr, nullptr, nullptr, nf32, nf32, Fb,
        n, h, n, 1.f, 0.f, 0.f, 1.f, 0.f, 0.f, 0.f, 0.f, 0.f, 0.f);
    // F2 = u@Mb + u + F -> F2b + F2Tb
    gemm_bf16<2, 1, 4><<<gHN, blk, 0, stream>>>(
        ub, MbT, nullptr, nullptr, F2b, nullptr, nullptr, F2Tb, nf32, Ff, ub,
        n, h, h, 1.f, 0.f, 1.f, 1.f, 0.f, 0.f, 0.f, 0.f, 0.f, 0.f);
    // v = Ma@F2 + F2 -> vb
    gemm_bf16<2, 1, 4><<<gHN, blk, 0, stream>>>(
        Mah, F2Tb, nullptr, nullptr, vb, nullptr, nullptr, nullptr, nf32, nf32, F2b,
        n, h, n, 1.f, 0.f, 0.f, 1.f, 0.f, 0.f, 0.f, 0.f, 0.f, 0.f);
    // F3 = v@Mb + v + F -> F3f (f32; read 3x by G2)
    gemm_bf16<2, 1, 4><<<gHN, blk, 0, stream>>>(
        vb, MbT, F3f, nullptr, nullptr, nullptr, nullptr, nullptr, nf32, Ff, vb,
        n, h, h, 1.f, 0.f, 1.f, 1.f, 0.f, 0.f, 0.f, 0.f, 0.f, 0.f);

    // ===== scan: 3 triple-steps (total 9 = int(1.0 // 0.1)) =====
    const float* zf = x;
    for (int s = 0; s < 3; ++s) {
        // G1: t = M3a@z + z -> tb16 (bf16 only; t-rounding ~1e-2, budget OK)
        gemm_bf16<2, 1, 4><<<gHN, blk, 0, stream>>>(
            M3ah, zt, nullptr, nullptr, tb16, nullptr, nullptr, nullptr,
            zf, nf32, nu16,
            n, h, n, 1.f, 1.f, 0.f, 0.f, 0.f, 0.f, 0.f, 0.f, 0.f, 0.f);
        // G2: z''' = t@M3b + t + F3 -> za (f32) + zt (bf16 T) [last: d_out]
        float* zout = (s == 2) ? (float*)d_out : za;
        gemm_bf16<2, 1, 4><<<gHN, blk, 0, stream>>>(
            tb16, M3bTb, zout, nullptr, nullptr, nullptr, nullptr,
            (s == 2) ? nullptr : zt, nf32, F3f, tb16,
            n, h, h, 1.f, 0.f, 1.f, 1.f, 0.f, 0.f, 0.f, 0.f, 0.f, 0.f);
        zf = za;
    }
}

// Round 14
// 296.215 us; speedup vs baseline: 1.8665x; 1.0911x over previous
//
#include <hip/hip_runtime.h>

typedef __attribute__((ext_vector_type(8))) short short8v;
typedef __attribute__((ext_vector_type(4))) float f32x4;

typedef const __attribute__((address_space(1))) void gvoid_t;
typedef __attribute__((address_space(3))) void svoid_t;

__device__ __forceinline__ unsigned short f2b(float f) {
    unsigned u = __float_as_uint(f);
    unsigned r = (u + 0x7fffu + ((u >> 16) & 1u)) >> 16;
    return (unsigned short)r;
}
__device__ __forceinline__ float b2f(unsigned short h) {
    return __uint_as_float((unsigned)h << 16);
}

// ---------------- elementwise / setup kernels ----------------

// Fused: X = dt*A = scale*sigmoid(alpha_i)*(adj - I) -> XAb (bf16) + XATb (bf16 T)
__global__ void k_build_AT(const float* __restrict__ adj,
                           const float* __restrict__ alpha,
                           unsigned short* __restrict__ XAb,
                           unsigned short* __restrict__ XATb,
                           int n, float scale)
{
    __shared__ float tile[32][33];
    int bx = blockIdx.x * 32, by = blockIdx.y * 32;
    int tx = threadIdx.x, ty = threadIdx.y;
    #pragma unroll
    for (int r = 0; r < 32; r += 8) {
        int i = by + ty + r, j = bx + tx;
        float s = 1.f / (1.f + expf(-alpha[i]));
        float v = scale * s * (adj[(size_t)i * n + j] - (i == j ? 1.f : 0.f));
        XAb[(size_t)i * n + j] = f2b(v);
        tile[ty + r][tx] = v;
    }
    __syncthreads();
    #pragma unroll
    for (int r = 0; r < 32; r += 8)
        XATb[(size_t)(bx + ty + r) * n + by + tx] = f2b(tile[tx][ty + r]);
}

__global__ void k_build_EW(const float* __restrict__ w,
                           const float* __restrict__ d,
                           unsigned short* __restrict__ Eb,
                           unsigned short* __restrict__ Edb,
                           float* __restrict__ Edf, int h)
{
    int j = blockIdx.x * 256 + threadIdx.x;
    int i = blockIdx.y;
    if (j >= h) return;
    size_t idx = (size_t)i * h + j;
    float e = w[idx] - (i == j ? 1.f : 0.f);
    float dc = fminf(fmaxf(d[j], 0.f), 1.f);
    Eb[idx] = f2b(e);
    float ed = e * dc;
    Edb[idx] = f2b(ed);
    Edf[idx] = ed;
}

__global__ void k_build_R(const float* __restrict__ Ed,
                          const float* __restrict__ d,
                          float* __restrict__ R, int h, float dt)
{
    __shared__ float tile[32][33];
    int bx = blockIdx.x * 32, by = blockIdx.y * 32;
    int tx = threadIdx.x, ty = threadIdx.y;
    #pragma unroll
    for (int r = 0; r < 32; r += 8)
        tile[ty + r][tx] = Ed[(size_t)(bx + ty + r) * h + by + tx];
    __syncthreads();
    #pragma unroll
    for (int r = 0; r < 32; r += 8) {
        int i = by + ty + r, j = bx + tx;
        float v = Ed[(size_t)i * h + j] + tile[tx][ty + r];
        if (i == j) v += fminf(fmaxf(d[i], 0.f), 1.f) - 1.f;
        R[(size_t)i * h + j] = dt * v;
    }
}

// two transposes in one dispatch
__global__ void k_tsplit2(const float* __restrict__ in0,
                          const float* __restrict__ in1,
                          unsigned short* __restrict__ out0,
                          unsigned short* __restrict__ out1, int R, int C)
{
    __shared__ float tile[32][33];
    int bx = blockIdx.x * 32, by = blockIdx.y * 32;
    int tx = threadIdx.x, ty = threadIdx.y;
    #pragma unroll
    for (int r = 0; r < 32; r += 8)
        tile[ty + r][tx] = in0[(size_t)(by + ty + r) * C + bx + tx];
    __syncthreads();
    #pragma unroll
    for (int r = 0; r < 32; r += 8)
        out0[(size_t)(bx + ty + r) * R + by + tx] = f2b(tile[tx][ty + r]);
    __syncthreads();
    #pragma unroll
    for (int r = 0; r < 32; r += 8)
        tile[ty + r][tx] = in1[(size_t)(by + ty + r) * C + bx + tx];
    __syncthreads();
    #pragma unroll
    for (int r = 0; r < 32; r += 8)
        out1[(size_t)(bx + ty + r) * R + by + tx] = f2b(tile[tx][ty + r]);
}

// ---------------- dual bf16 MFMA GEMM ----------------
// Two independent GEMMs in ONE launch (blocks [0,nb0) -> a0, rest -> a1) so
// small/serial-chain GEMMs hide inside big dispatches (latency-bound regime:
// TLP is the binding resource, R8-R12 evidence). Per-GEMM structure identical
// to R13: BK=64, 2-buffer counted-vmcnt pipeline, XOR-swizzled staging+reads
// (0 bank conflicts, R5-R13), XCD row-stripe swizzle on the logical grid.
// v  = alpha*acc + beta*D + g2*D2 + g3*b2f(Db) -> C, Cb, CbT
// v2 = pa*acc + pb*D + pc*b2f(Db)              -> C2, Cb2
// v3 = qa*acc + qb*D + qc*b2f(Db)              -> Cb3

struct GArgs {
    const unsigned short *A, *BT;
    float *C, *C2;
    unsigned short *Cb, *Cb2, *Cb3, *CbT;
    const float *D, *D2;
    const unsigned short *Db;
    int M, N, K, ngx, ngy;
    float alpha, beta, g2, g3, pa, pb, pc, qa, qb, qc;
};

template<int FM, int FN, int MW>
__global__ __launch_bounds__(256, MW)
void gemm2(GArgs a0, GArgs a1, int nb0)
{
    constexpr int BM = FM * 32, BN = FN * 32, BK = 64;
    constexpr int AIT = BM * BK / (8 * 256);
    constexpr int BIT = BN * BK / (8 * 256);
    constexpr int LPT = AIT + BIT;
    __shared__ unsigned short As[2][BM * BK];
    __shared__ unsigned short Bs[2][BN * BK];

    const bool second = ((int)blockIdx.x >= nb0);
    const GArgs& a = second ? a1 : a0;
    int bid = (int)blockIdx.x - (second ? nb0 : 0);

    // XCD row-stripe swizzle on the logical (ngy x ngx) grid (ngy % 8 == 0)
    int rpx = a.ngy >> 3;
    int q = bid & 7, c = bid >> 3;
    int by = q * rpx + (c % rpx);
    int bx = c / rpx;

    const int tid  = threadIdx.x;
    const int lane = tid & 63;
    const int wave = tid >> 6;
    const int wr = wave >> 1, wc = wave & 1;
    const int l16 = lane & 15, l4 = lane >> 4;
    const int brow = by * BM, bcol = bx * BN;
    const int K = a.K, N = a.N, M = a.M;

    f32x4 acc[FM][FN];
    #pragma unroll
    for (int m = 0; m < FM; ++m)
        #pragma unroll
        for (int j = 0; j < FN; ++j)
            acc[m][j] = (f32x4){0.f, 0.f, 0.f, 0.f};

    const unsigned short* Ab = a.A + (size_t)brow * K;
    const unsigned short* Bb = a.BT + (size_t)bcol * K;
    const int nt = K / BK;

    auto stage = [&](int b, int k0) {
        #pragma unroll
        for (int it = 0; it < AIT; ++it) {
            int cb = it * 256 + wave * 64;
            int ch = cb + lane;
            int r = ch >> 3, cc = ch & 7;
            int cs = cc ^ (r & 7);
            __builtin_amdgcn_global_load_lds(
                (gvoid_t*)(Ab + (size_t)r * K + k0 + cs * 8),
                (svoid_t*)(&As[b][cb * 8]), 16, 0, 0);
        }
        #pragma unroll
        for (int it = 0; it < BIT; ++it) {
            int cb = it * 256 + wave * 64;
            int ch = cb + lane;
            int r = ch >> 3, cc = ch & 7;
            int cs = cc ^ (r & 7);
            __builtin_amdgcn_global_load_lds(
                (gvoid_t*)(Bb + (size_t)r * K + k0 + cs * 8),
                (svoid_t*)(&Bs[b][cb * 8]), 16, 0, 0);
        }
    };

    stage(0, 0);
    stage(1, BK);

    for (int t = 0; t < nt; ++t) {
        const int cur = t & 1;
        if (t + 1 < nt) {
            asm volatile("s_waitcnt vmcnt(%0)" :: "i"(LPT) : "memory");
        } else {
            asm volatile("s_waitcnt vmcnt(0)" ::: "memory");
        }
        __builtin_amdgcn_s_barrier();
        asm volatile("" ::: "memory");
        __builtin_amdgcn_sched_barrier(0);

        short8v af[FM][2], bf[FN][2];
        #pragma unroll
        for (int m = 0; m < FM; ++m) {
            int r = wr * FM * 16 + m * 16 + l16;
            #pragma unroll
            for (int hf = 0; hf < 2; ++hf) {
                int cs = (hf * 4 + l4) ^ (r & 7);
                af[m][hf] = *(const short8v*)&As[cur][r * BK + cs * 8];
            }
        }
        #pragma unroll
        for (int j = 0; j < FN; ++j) {
            int r = wc * FN * 16 + j * 16 + l16;
            #pragma unroll
            for (int hf = 0; hf < 2; ++hf) {
                int cs = (hf * 4 + l4) ^ (r & 7);
                bf[j][hf] = *(const short8v*)&Bs[cur][r * BK + cs * 8];
            }
        }
        __builtin_amdgcn_s_setprio(1);
        #pragma unroll
        for (int hf = 0; hf < 2; ++hf)
            #pragma unroll
            for (int m = 0; m < FM; ++m)
                #pragma unroll
                for (int j = 0; j < FN; ++j)
                    acc[m][j] = __builtin_amdgcn_mfma_f32_16x16x32_bf16(
                        af[m][hf], bf[j][hf], acc[m][j], 0, 0, 0);
        __builtin_amdgcn_s_setprio(0);
        __builtin_amdgcn_sched_barrier(0);
        __builtin_amdgcn_s_barrier();
        asm volatile("" ::: "memory");
        if (t + 2 < nt) stage(cur, (t + 2) * BK);
    }

    #pragma unroll
    for (int m = 0; m < FM; ++m) {
        #pragma unroll
        for (int j = 0; j < FN; ++j) {
            const int row0 = brow + wr * FM * 16 + m * 16 + l4 * 4;
            const int col  = bcol + wc * FN * 16 + j * 16 + l16;
            float vv[4];
            #pragma unroll
            for (int q2 = 0; q2 < 4; ++q2) {
                size_t idx = (size_t)(row0 + q2) * N + col;
                float a0v = acc[m][j][q2];
                float v = a.alpha * a0v;
                float dv = 0.f, dbv = 0.f;
                if (a.D)  { dv = a.D[idx]; v = fmaf(a.beta, dv, v); }
                if (a.D2) v = fmaf(a.g2, a.D2[idx], v);
                if (a.Db) { dbv = b2f(a.Db[idx]); v = fmaf(a.g3, dbv, v); }
                vv[q2] = v;
                if (a.C)  a.C[idx] = v;
                if (a.Cb) a.Cb[idx] = f2b(v);
                if (a.C2 || a.Cb2) {
                    float v2 = a.pa * a0v;
                    if (a.D)  v2 = fmaf(a.pb, dv, v2);
                    if (a.Db) v2 = fmaf(a.pc, dbv, v2);
                    if (a.C2)  a.C2[idx] = v2;
                    if (a.Cb2) a.Cb2[idx] = f2b(v2);
                }
                if (a.Cb3) {
                    float v3 = a.qa * a0v;
                    if (a.D)  v3 = fmaf(a.qb, dv, v3);
                    if (a.Db) v3 = fmaf(a.qc, dbv, v3);
                    a.Cb3[idx] = f2b(v3);
                }
            }
            if (a.CbT) {
                ushort4 t4;
                t4.x = f2b(vv[0]); t4.y = f2b(vv[1]);
                t4.z = f2b(vv[2]); t4.w = f2b(vv[3]);
                *reinterpret_cast<ushort4*>(&a.CbT[(size_t)col * M + row0]) = t4;
            }
        }
    }
}

// ---------------- host orchestration ----------------

typedef unsigned short u16;

static GArgs mk(const u16* A, const u16* BT, float* C, float* C2,
                u16* Cb, u16* Cb2, u16* Cb3, u16* CbT,
                const float* D, const float* D2, const u16* Db,
                int M, int N, int K, int ngx, int ngy,
                float alpha, float beta, float g2, float g3,
                float pa, float pb, float pc,
                float qa, float qb, float qc)
{
    GArgs a;
    a.A = A; a.BT = BT; a.C = C; a.C2 = C2;
    a.Cb = Cb; a.Cb2 = Cb2; a.Cb3 = Cb3; a.CbT = CbT;
    a.D = D; a.D2 = D2; a.Db = Db;
    a.M = M; a.N = N; a.K = K; a.ngx = ngx; a.ngy = ngy;
    a.alpha = alpha; a.beta = beta; a.g2 = g2; a.g3 = g3;
    a.pa = pa; a.pb = pb; a.pc = pc; a.qa = qa; a.qb = qb; a.qc = qc;
    return a;
}

extern "C" void kernel_launch(void* const* d_in, const int* in_sizes, int n_in,
                              void* d_out, int out_size, void* d_ws, size_t ws_size,
                              hipStream_t stream)
{
    const float* x     = (const float*)d_in[0];   // [n, h]
    const float* x0    = (const float*)d_in[1];   // [n, h]
    const float* adj   = (const float*)d_in[2];   // [n, n]
    const float* alpha = (const float*)d_in[3];   // [n]
    const float* w     = (const float*)d_in[4];   // [h, h]
    const float* dvec  = (const float*)d_in[5];   // [h]

    const int n = in_sizes[3];      // 2048
    const int h = in_sizes[5];      // 1024
    const size_t MB = 1u << 20;
    char* ws = (char*)d_ws;

    // ---- workspace: non-overlapping regions (MiB offsets; peak 136 MiB) ----
    u16*   XAb   = (u16*)(ws + 0 * MB);      // 8
    u16*   XATb  = (u16*)(ws + 8 * MB);      // 8
    u16*   Mah   = (u16*)(ws + 16 * MB);     // 8
    u16*   Pmb   = (u16*)(ws + 24 * MB);     // 8
    u16*   M3ah  = (u16*)(ws + 32 * MB);     // 8
    u16*   MbT   = (u16*)(ws + 40 * MB);     // 2
    u16*   M3bTb = (u16*)(ws + 42 * MB);     // 2
    u16*   Eb_   = (u16*)(ws + 44 * MB);     // 2
    u16*   Edb   = (u16*)(ws + 46 * MB);     // 2
    float* Edf   = (float*)(ws + 48 * MB);   // 4
    float* R     = (float*)(ws + 52 * MB);   // 4
    float* XBf   = (float*)(ws + 56 * MB);   // 4
    u16*   XBb   = (u16*)(ws + 60 * MB);     // 2
    u16*   XBT   = (u16*)(ws + 62 * MB);     // 2
    float* P2f   = (float*)(ws + 64 * MB);   // 4
    u16*   P2b   = (u16*)(ws + 68 * MB);     // 2
    float* P3f   = (float*)(ws + 70 * MB);   // 4
    u16*   P3b   = (u16*)(ws + 74 * MB);     // 2
    u16*   x0T   = (u16*)(ws + 76 * MB);     // 4
    float* Ff    = (float*)(ws + 80 * MB);   // 8
    u16*   Fb    = (u16*)(ws + 88 * MB);     // 4
    u16*   FTb   = (u16*)(ws + 92 * MB);     // 4
    u16*   ub    = (u16*)(ws + 96 * MB);     // 4
    u16*   F2b   = (u16*)(ws + 100 * MB);    // 4
    u16*   F2Tb  = (u16*)(ws + 104 * MB);    // 4
    u16*   vb    = (u16*)(ws + 108 * MB);    // 4
    float* F3f   = (float*)(ws + 112 * MB);  // 8
    u16*   zt    = (u16*)(ws + 120 * MB);    // 4
    u16*   tb16  = (u16*)(ws + 124 * MB);    // 4
    float* za    = (float*)(ws + 128 * MB);  // 8

    const dim3 blk(256);
    const float dt = 0.1f;
    const u16* nu = nullptr;
    const float* nf = nullptr;

    // ===== setup =====
    k_build_AT<<<dim3(n / 32, n / 32), dim3(32, 8), 0, stream>>>(
        adj, alpha, XAb, XATb, n, 0.5f * dt);
    k_build_EW<<<dim3(h / 256, h), blk, 0, stream>>>(w, dvec, Eb_, Edb, Edf, h);
    k_build_R<<<dim3(h / 32, h / 32), dim3(32, 8), 0, stream>>>(Edf, dvec, R, h, dt);
    k_tsplit2<<<dim3(h / 32, n / 32), dim3(32, 8), 0, stream>>>(
        x0, x, x0T, zt, n, h);

    // ===== P1: A1 (n^3, 64x64) || B1 (h^3, 64x64) =====
    // A1: acc = X^2; Ma = X + X^2/2 -> Mah; Pm = X/2 + X^2/6 -> Pmb;
    //     M3a = 3X + 4.5X^2 -> M3ah
    // B1: XB = dt*(Ed @ E^T) + R -> XBf + XBb + XBT
    {
        GArgs gA1 = mk(XAb, XATb, nullptr, nullptr, Mah, Pmb, M3ah, nullptr,
                       nf, nf, XAb, n, n, n, n / 64, n / 64,
                       0.5f, 0.f, 0.f, 1.f, 1.f / 6.f, 0.f, 0.5f, 4.5f, 0.f, 3.f);
        GArgs gB1 = mk(Edb, Eb_, XBf, nullptr, XBb, nullptr, nullptr, XBT,
                       R, nf, nu, h, h, h, h / 64, h / 64,
                       dt, 1.f, 0.f, 0.f, 0.f, 0.f, 0.f, 0.f, 0.f, 0.f);
        gemm2<2, 2, 4><<<dim3(1024 + 256), blk, 0, stream>>>(gA1, gB1, 1024);
    }

    // ===== P2: F (K=2048) || B2 (h^3, 64x32) =====
    // F = dt*(Pm@x0) + dt*x0 -> Ff + Fb + FTb ; B2: P2 = XB^2 -> P2f + P2b
    {
        GArgs gF = mk(Pmb, x0T, Ff, nullptr, Fb, nullptr, nullptr, FTb,
                      x0, nf, nu, n, h, n, h / 32, n / 64,
                      dt, dt, 0.f, 0.f, 0.f, 0.f, 0.f, 0.f, 0.f, 0.f);
        GArgs gB2 = mk(XBb, XBT, P2f, nullptr, P2b, nullptr, nullptr, nullptr,
                       nf, nf, nu, h, h, h, h / 32, h / 64,
                       1.f, 0.f, 0.f, 0.f, 0.f, 0.f, 0.f, 0.f, 0.f, 0.f);
        gemm2<2, 1, 4><<<dim3(1024 + 512), blk, 0, stream>>>(gF, gB2, 1024);
    }

    // ===== P3: u (K=2048) || B3 (h^3) =====
    // u = Ma@F + F -> ub
    // B3: acc = XB^3; MbT = acc/6 + XB + XB^2/2 (CbT); P3 = acc (C2+Cb2)
    {
        GArgs gU = mk(Mah, FTb, nullptr, nullptr, ub, nullptr, nullptr, nullptr,
                      nf, nf, Fb, n, h, n, h / 32, n / 64,
                      1.f, 0.f, 0.f, 1.f, 0.f, 0.f, 0.f, 0.f, 0.f, 0.f);
        GArgs gB3 = mk(P2b, XBT, nullptr, P3f, nullptr, P3b, nullptr, MbT,
                       XBf, P2f, nu, h, h, h, h / 32, h / 64,
                       1.f / 6.f, 1.f, 0.5f, 0.f, 1.f, 0.f, 0.f, 0.f, 0.f, 0.f);
        gemm2<2, 1, 4><<<dim3(1024 + 512), blk, 0, stream>>>(gU, gB3, 1024);
    }

    // ===== P4: F2 (K=1024) || B4 (h^3) =====
    // F2 = u@Mb + u + F -> F2b + F2Tb
    // B4: acc = XB^4; M3bT = 3.375 acc + 4.5 XB^3 + 4.5 XB^2 + 3 XB
    {
        GArgs gF2 = mk(ub, MbT, nullptr, nullptr, F2b, nullptr, nullptr, F2Tb,
                       nf, Ff, ub, n, h, h, h / 32, n / 64,
                       1.f, 0.f, 1.f, 1.f, 0.f, 0.f, 0.f, 0.f, 0.f, 0.f);
        GArgs gB4 = mk(P3b, XBT, nullptr, nullptr, nullptr, nullptr, nullptr, M3bTb,
                       P3f, P2f, XBb, h, h, h, h / 32, h / 64,
                       3.375f, 4.5f, 4.5f, 3.f, 0.f, 0.f, 0.f, 0.f, 0.f, 0.f);
        gemm2<2, 1, 4><<<dim3(1024 + 512), blk, 0, stream>>>(gF2, gB4, 1024);
    }

    // ===== P5: v (K=2048) || G1 step 0 (K=2048) =====
    // v = Ma@F2 + F2 -> vb ;  t0 = M3a@z + z -> tb16
    {
        GArgs gV = mk(Mah, F2Tb, nullptr, nullptr, vb, nullptr, nullptr, nullptr,
                      nf, nf, F2b, n, h, n, h / 32, n / 64,
                      1.f, 0.f, 0.f, 1.f, 0.f, 0.f, 0.f, 0.f, 0.f, 0.f);
        GArgs gG1 = mk(M3ah, zt, nullptr, nullptr, tb16, nullptr, nullptr, nullptr,
                       x, nf, nu, n, h, n, h / 32, n / 64,
                       1.f, 1.f, 0.f, 0.f, 0.f, 0.f, 0.f, 0.f, 0.f, 0.f);
        gemm2<2, 1, 4><<<dim3(1024 + 1024), blk, 0, stream>>>(gV, gG1, 1024);
    }

    // ===== F3 = v@Mb + v + F (K=1024) =====
    {
        GArgs g = mk(vb, MbT, F3f, nullptr, nullptr, nullptr, nullptr, nullptr,
                     nf, Ff, vb, n, h, h, h / 32, n / 64,
                     1.f, 0.f, 1.f, 1.f, 0.f, 0.f, 0.f, 0.f, 0.f, 0.f);
        gemm2<2, 1, 4><<<dim3(1024), blk, 0, stream>>>(g, g, 1024);
    }

    // ===== scan remainder: G2, (G1, G2) x 2 =====
    for (int s = 0; s < 3; ++s) {
        if (s > 0) {
            // G1: t = M3a@z + z -> tb16
            GArgs g = mk(M3ah, zt, nullptr, nullptr, tb16, nullptr, nullptr,
                         nullptr, za, nf, nu, n, h, n, h / 32, n / 64,
                         1.f, 1.f, 0.f, 0.f, 0.f, 0.f, 0.f, 0.f, 0.f, 0.f);
            gemm2<2, 1, 4><<<dim3(1024), blk, 0, stream>>>(g, g, 1024);
        }
        // G2: z''' = t@M3b + t + F3 -> za (+ zt for next step) [last: d_out]
        float* zout = (s == 2) ? (float*)d_out : za;
        GArgs g = mk(tb16, M3bTb, zout, nullptr, nullptr, nullptr, nullptr,
                     (s == 2) ? nullptr : zt, nf, F3f, tb16,
                     n, h, h, h / 32, n / 64,
                     1.f, 0.f, 1.f, 1.f, 0.f, 0.f, 0.f, 0.f, 0.f, 0.f);
        gemm2<2, 1, 4><<<dim3(1024), blk, 0, stream>>>(g, g, 1024);
    }
}